// Round 8
// baseline (199.405 us; speedup 1.0000x reference)
//
#include <hip/hip_runtime.h>
#include <hip/hip_bf16.h>

// RelationAttn: out = softmax_causal((enc @ R) @ enc^T) @ enc
// enc: [8,2048,1024] f32, R: [1024,1024] f32, out: [8,2048,1024] f32
//
// f16 pipeline, all GEMMs m97-style + T2 swizzle + R8: T3-minimal 2-phase
// double-buffered prefetch (stage t+1 BEFORE compute t; ONE barrier/K-step).
//   P0: enc -> enc_h (f16, d_out upper 32MB) + enc_t (f16 transposed, ws)
//   P1: R   -> R_t (f16 transposed, ws)
//   K1: Q_h = enc_h @ R_t^T      -> d_out lower 32MB (f16)
//   K2: S = Q_h @ enc_h^T causal -> ws (f16, lower-tri 128^2 tiles)
//   K3: P = softmax_row(S) in place
//   K4: out = P @ enc_t^T        -> d_out (f32, overwrites Q_h/enc_h)
// Fallback (ws < 98MB): R5 pipeline (f32-staged GEMMs).

typedef __attribute__((ext_vector_type(4))) float f32x4;
typedef __attribute__((ext_vector_type(4))) unsigned u32x4;
typedef __attribute__((ext_vector_type(8))) __fp16 f16x8;
typedef __attribute__((ext_vector_type(4))) __fp16 f16x4;
typedef __attribute__((ext_vector_type(2))) __fp16 f16x2;

#define MFMA16H(A, B, C) __builtin_amdgcn_mfma_f32_16x16x32_f16(A, B, C, 0, 0, 0)

__device__ __forceinline__ f16x4 cvt4h(f32x4 a) {
    union { f16x4 v; f16x2 h[2]; } r;
    r.h[0] = __builtin_amdgcn_cvt_pkrtz(a[0], a[1]);
    r.h[1] = __builtin_amdgcn_cvt_pkrtz(a[2], a[3]);
    return r.v;
}

// async global->LDS, 16B per lane; lds dest = wave-uniform base + lane*16
__device__ __forceinline__ void gload16(const void* g, void* l) {
    __builtin_amdgcn_global_load_lds(
        (const __attribute__((address_space(1))) unsigned*)g,
        (__attribute__((address_space(3))) unsigned*)l, 16, 0, 0);
}

// ---------------------------------------------------------------------------
// P0/P1: transpose + convert. src f32 [bz][R][C] -> dstT f16 [bz][C][R]
// and (if dstH) dstH f16 [bz][R][C]. 64x64 tiles, swizzled LDS.
// ---------------------------------------------------------------------------
__global__ __launch_bounds__(256) void transpose_cvt_kernel(
    const float* __restrict__ src, __fp16* __restrict__ dstT,
    __fp16* __restrict__ dstH, int R, int C)
{
    __shared__ __align__(16) char lt[64 * 128];  // [r][c] f16, XOR-swizzled
    const int t = threadIdx.x;
    const int bz = blockIdx.z;
    const int r0 = blockIdx.x * 64, c0 = blockIdx.y * 64;
    const size_t so = (size_t)bz * R * C;
    const int tr = t >> 4;
    const int tc4 = (t & 15) * 4;
#pragma unroll
    for (int p = 0; p < 4; ++p) {
        int rl = tr + 16 * p;
        f32x4 x = *(const f32x4*)(src + so + (size_t)(r0 + rl) * C + c0 + tc4);
        f16x4 h = cvt4h(x);
        if (dstH) *(f16x4*)(dstH + so + (size_t)(r0 + rl) * C + c0 + tc4) = h;
        *(f16x4*)(lt + rl * 128 + ((tc4 * 2) ^ ((rl & 7) << 4))) = h;
    }
    __syncthreads();
#pragma unroll
    for (int p = 0; p < 4; ++p) {
        int dl = tr + 16 * p;
#pragma unroll
        for (int j = 0; j < 4; ++j) {
            int kl = (t & 15) + 16 * j;
            __fp16 v = *(const __fp16*)(lt + kl * 128 + ((dl * 2) ^ ((kl & 7) << 4)));
            dstT[so + (size_t)(c0 + dl) * R + r0 + kl] = v;
        }
    }
}

// ---------------------------------------------------------------------------
// Unified f16 GEMM core: C(128x128) = A(128xK) @ B(128xK)^T.
// m97 staging (global_load_lds w16, pre-swizzled source) + XOR-swizzled reads
// + double-buffered LDS with prefetch-before-compute (one barrier per K-step).
// CMODE: 0 = f16 out; 1 = f16 out + causal diag mask; 2 = f32 out.
// ---------------------------------------------------------------------------
template <int CMODE>
__device__ __forceinline__ void gemm_core(
    const __fp16* __restrict__ A, const __fp16* __restrict__ B,
    char* __restrict__ Cptr, int ldA, int ldB, int ldC, int K, bool diag)
{
    __shared__ __align__(16) char sA[2][128 * 128];  // 2 x (128 rows x 64 f16)
    __shared__ __align__(16) char sB[2][128 * 128];
    const int t = threadIdx.x;
    const int w = t >> 6, l = t & 63;
    const int l15 = l & 15, lg = l >> 4;
    const int r0 = (w >> 1) * 64, c0 = (w & 1) * 64;
    const int swz = (l15 & 7) << 4;   // read-side XOR (row&7 == l15&7)

    f32x4 acc[4][4];
#pragma unroll
    for (int i = 0; i < 4; ++i)
#pragma unroll
        for (int j = 0; j < 4; ++j) acc[i][j] = (f32x4){0.f, 0.f, 0.f, 0.f};

    // staging: wave w rows 32w..32w+31; instr i rows 32w+8i..+7;
    // lane l: row += l>>3, SOURCE granule (l&7)^(l>>3) (inverse swizzle).
    const int strow = 32 * w + (l >> 3);
    const int gsrc = (((l & 7) ^ (l >> 3)) << 3);  // element offset (x8 f16)
    const __fp16* pa = A + (size_t)strow * ldA + gsrc;
    const __fp16* pb = B + (size_t)strow * ldB + gsrc;

    const int nt = K >> 6;
    // prologue: stage tile 0 into buffer 0
#pragma unroll
    for (int i = 0; i < 4; ++i) {
        gload16(pa + (size_t)(8 * i) * ldA, sA[0] + w * 4096 + i * 1024);
        gload16(pb + (size_t)(8 * i) * ldB, sB[0] + w * 4096 + i * 1024);
    }
    __syncthreads();  // drains vmcnt -> tile 0 visible

    for (int tt = 0; tt < nt; ++tt) {
        const int cur = tt & 1;
        // issue next tile's staging FIRST; latency hides under compute below
        if (tt + 1 < nt) {
            const int kk = 64 * (tt + 1);
#pragma unroll
            for (int i = 0; i < 4; ++i) {
                gload16(pa + (size_t)(8 * i) * ldA + kk, sA[cur ^ 1] + w * 4096 + i * 1024);
                gload16(pb + (size_t)(8 * i) * ldB + kk, sB[cur ^ 1] + w * 4096 + i * 1024);
            }
        }
        // compute current tile
#pragma unroll
        for (int ks = 0; ks < 2; ++ks) {
            f16x8 af[4], bf[4];
#pragma unroll
            for (int mt = 0; mt < 4; ++mt)
                af[mt] = *(const f16x8*)(sA[cur] + (r0 + 16 * mt + l15) * 128 + ((64 * ks + 16 * lg) ^ swz));
#pragma unroll
            for (int nt2 = 0; nt2 < 4; ++nt2)
                bf[nt2] = *(const f16x8*)(sB[cur] + (c0 + 16 * nt2 + l15) * 128 + ((64 * ks + 16 * lg) ^ swz));
#pragma unroll
            for (int mt = 0; mt < 4; ++mt)
#pragma unroll
                for (int nt2 = 0; nt2 < 4; ++nt2)
                    acc[mt][nt2] = MFMA16H(af[mt], bf[nt2], acc[mt][nt2]);
        }
        __syncthreads();  // drains vmcnt (next tile landed) + lgkm; one barrier/K-step
    }
    // C/D layout: col = l15, row = 4*lg + rg
#pragma unroll
    for (int mt = 0; mt < 4; ++mt)
#pragma unroll
        for (int nt2 = 0; nt2 < 4; ++nt2)
#pragma unroll
            for (int rg = 0; rg < 4; ++rg) {
                int rr = r0 + 16 * mt + 4 * lg + rg;
                int cc = c0 + 16 * nt2 + l15;
                float v = acc[mt][nt2][rg];
                if (CMODE == 2) {
                    *(float*)(Cptr + ((size_t)rr * ldC + cc) * 4) = v;
                } else {
                    if (CMODE == 1 && diag && cc > rr) v = -30000.f;
                    *(__fp16*)(Cptr + ((size_t)rr * ldC + cc) * 2) = (__fp16)v;
                }
            }
}

// K1: Q_h = enc_h @ R_t^T  (16384x1024 @ 1024x1024)
__global__ __launch_bounds__(256) void gemm_qr(
    const __fp16* __restrict__ encH, const __fp16* __restrict__ Rt,
    __fp16* __restrict__ Qh)
{
    const int bm = ((int)blockIdx.x >> 3) * 128;
    const int bn = ((int)blockIdx.x & 7) * 128;
    gemm_core<0>(encH + (size_t)bm * 1024, Rt + (size_t)bn * 1024,
                 (char*)(Qh + (size_t)bm * 1024 + bn), 1024, 1024, 1024, 1024, false);
}

// K2: S = Q_h @ enc_h^T, causal lower-tri tiles. batch = bid&7 (XCD affinity).
__global__ __launch_bounds__(256) void gemm_s(
    const __fp16* __restrict__ Qh, const __fp16* __restrict__ encH,
    __fp16* __restrict__ S)
{
    const int b = (int)blockIdx.x & 7;
    int rem = 135 - ((int)blockIdx.x >> 3);
    int qt = 0;
    while (rem > qt) { rem -= qt + 1; ++qt; }
    const int kt = rem;
    const size_t bo = (size_t)b * 2048 * 1024;
    const size_t so = (size_t)b * 2048 * 2048;
    gemm_core<1>(Qh + bo + (size_t)(qt * 128) * 1024,
                 encH + bo + (size_t)(kt * 128) * 1024,
                 (char*)(S + so + (size_t)(qt * 128) * 2048 + kt * 128),
                 1024, 1024, 2048, 1024, qt == kt);
}

// K4: out = P @ enc_t^T. Variable K = 128*(qtb+1), heavy-first.
__global__ __launch_bounds__(256) void gemm_pv(
    const __fp16* __restrict__ P, const __fp16* __restrict__ encT,
    float* __restrict__ out)
{
    const int b = (int)blockIdx.x & 7;
    const int r = (int)blockIdx.x >> 3;      // 0..127
    const int qtb = 15 - (r >> 3);
    const int dblk = r & 7;
    const size_t so = (size_t)b * 2048 * 2048;
    const size_t to = (size_t)b * 1024 * 2048;
    const int K = 128 * (qtb + 1);
    gemm_core<2>(P + so + (size_t)(qtb * 128) * 2048,
                 encT + to + (size_t)(dblk * 128) * 2048,
                 (char*)(out + (size_t)b * 2048 * 1024 + (size_t)(qtb * 128) * 1024 + dblk * 128),
                 2048, 2048, 1024, K, false);
}

// ---------------------------------------------------------------------------
// K3: in-place row softmax over S (f16). One wave per row; L = roundup(r+1,128).
// ---------------------------------------------------------------------------
__global__ __launch_bounds__(256) void softmax_kernel(__fp16* __restrict__ S)
{
    const int t = threadIdx.x;
    const int wv = t >> 6, l = t & 63;
    const int r = blockIdx.x * 4 + wv;
    const int b = blockIdx.y;
    __fp16* row = S + ((size_t)b * 2048 + r) * 2048;
    const int L = ((r >> 7) + 1) << 7;

    float v[4][8];
    float mx = -1e30f;
#pragma unroll
    for (int i = 0; i < 4; ++i) {
        int c0 = 8 * l + 512 * i;
        if (c0 < L) {
            f16x8 h = *reinterpret_cast<const f16x8*>(row + c0);
#pragma unroll
            for (int j = 0; j < 8; ++j) { v[i][j] = (float)h[j]; mx = fmaxf(mx, v[i][j]); }
        } else {
#pragma unroll
            for (int j = 0; j < 8; ++j) v[i][j] = -1e30f;
        }
    }
#pragma unroll
    for (int off = 1; off < 64; off <<= 1) mx = fmaxf(mx, __shfl_xor(mx, off));
    float sm = 0.f;
#pragma unroll
    for (int i = 0; i < 4; ++i)
#pragma unroll
        for (int j = 0; j < 8; ++j) { v[i][j] = __expf(v[i][j] - mx); sm += v[i][j]; }
#pragma unroll
    for (int off = 1; off < 64; off <<= 1) sm += __shfl_xor(sm, off);
    const float inv = 1.f / sm;
#pragma unroll
    for (int i = 0; i < 4; ++i) {
        int c0 = 8 * l + 512 * i;
        if (c0 < L) {
            union { f16x8 v8; f16x2 h[4]; } o;
#pragma unroll
            for (int j = 0; j < 4; ++j)
                o.h[j] = __builtin_amdgcn_cvt_pkrtz(v[i][2 * j] * inv, v[i][2 * j + 1] * inv);
            *reinterpret_cast<f16x8*>(row + c0) = o.v8;
        }
    }
}

// ===========================================================================
// Fallback path (R5): f32-staged GEMMs, used only if ws < 98MB.
// ===========================================================================
__global__ __launch_bounds__(256) void qr_gemm_kernel(
    const float* __restrict__ A, const float* __restrict__ B, float* C)
{
    __shared__ __align__(16) char sA[128 * 64];
    __shared__ __align__(16) char sB[128 * 64];
    const int t = threadIdx.x;
    const int w = t >> 6, l = t & 63;
    const int l15 = l & 15, lg = l >> 4;
    const int bm = blockIdx.x * 128;
    const int bn = blockIdx.y * 128;

    f32x4 acc[4][4];
#pragma unroll
    for (int i = 0; i < 4; ++i)
#pragma unroll
        for (int j = 0; j < 4; ++j) acc[i][j] = (f32x4){0.f, 0.f, 0.f, 0.f};

    const int kq = 4 * (t & 7);
    const int i2 = t >> 3;

    for (int kk = 0; kk < 1024; kk += 32) {
#pragma unroll
        for (int it = 0; it < 4; ++it) {
            int m = i2 + 32 * it;
            f32x4 x = *reinterpret_cast<const f32x4*>(&A[(size_t)(bm + m) * 1024 + kk + kq]);
            *reinterpret_cast<f16x4*>(sA + m * 64 + ((2 * kq) ^ (((m >> 1) & 3) << 4))) = cvt4h(x);
        }
        {
            int n0 = 4 * i2;
            f32x4 x[4];
#pragma unroll
            for (int r = 0; r < 4; ++r)
                x[r] = *reinterpret_cast<const f32x4*>(&B[(size_t)(kk + kq + r) * 1024 + bn + n0]);
#pragma unroll
            for (int j = 0; j < 4; ++j) {
                int n = n0 + j;
                union { f16x4 v; f16x2 h[2]; } s;
                s.h[0] = __builtin_amdgcn_cvt_pkrtz(x[0][j], x[1][j]);
                s.h[1] = __builtin_amdgcn_cvt_pkrtz(x[2][j], x[3][j]);
                *reinterpret_cast<f16x4*>(sB + n * 64 + ((2 * kq) ^ (((n >> 1) & 3) << 4))) = s.v;
            }
        }
        __syncthreads();
        f16x8 af[4], bfv[4];
        const int r0 = (w >> 1) * 64, c0 = (w & 1) * 64;
#pragma unroll
        for (int mt = 0; mt < 4; ++mt) {
            int m = r0 + 16 * mt + l15;
            af[mt] = *reinterpret_cast<f16x8*>(sA + m * 64 + ((16 * lg) ^ (((m >> 1) & 3) << 4)));
        }
#pragma unroll
        for (int nt = 0; nt < 4; ++nt) {
            int n = c0 + 16 * nt + l15;
            bfv[nt] = *reinterpret_cast<f16x8*>(sB + n * 64 + ((16 * lg) ^ (((n >> 1) & 3) << 4)));
        }
#pragma unroll
        for (int mt = 0; mt < 4; ++mt)
#pragma unroll
            for (int nt = 0; nt < 4; ++nt)
                acc[mt][nt] = MFMA16H(af[mt], bfv[nt], acc[mt][nt]);
        __syncthreads();
    }
#pragma unroll
    for (int mt = 0; mt < 4; ++mt)
#pragma unroll
        for (int nt = 0; nt < 4; ++nt)
#pragma unroll
            for (int rg = 0; rg < 4; ++rg) {
                int row = bm + (w >> 1) * 64 + 16 * mt + 4 * lg + rg;
                int col = bn + (w & 1) * 64 + 16 * nt + l15;
                C[(size_t)row * 1024 + col] = acc[mt][nt][rg];
            }
}

__global__ __launch_bounds__(256) void s_gemm_kernel(
    const float* __restrict__ Q, const float* __restrict__ enc, __fp16* __restrict__ S)
{
    __shared__ __align__(16) char sA[128 * 64];
    __shared__ __align__(16) char sB[128 * 64];
    const int t = threadIdx.x;
    const int w = t >> 6, l = t & 63;
    const int l15 = l & 15, lg = l >> 4;

    int rem = 135 - (int)blockIdx.x;
    int qt = 0;
    while (rem > qt) { rem -= qt + 1; ++qt; }
    const int kt = rem;
    const int b = blockIdx.y;
    const float* Arow = Q + ((size_t)b * 2048 + qt * 128) * 1024;
    const float* Brow = enc + ((size_t)b * 2048 + kt * 128) * 1024;

    f32x4 acc[4][4];
#pragma unroll
    for (int i = 0; i < 4; ++i)
#pragma unroll
        for (int j = 0; j < 4; ++j) acc[i][j] = (f32x4){0.f, 0.f, 0.f, 0.f};

    const int kq = 4 * (t & 7);
    const int i2 = t >> 3;

    for (int kk = 0; kk < 1024; kk += 32) {
#pragma unroll
        for (int it = 0; it < 4; ++it) {
            int m = i2 + 32 * it;
            int sw = (2 * kq) ^ (((m >> 1) & 3) << 4);
            f32x4 xa = *reinterpret_cast<const f32x4*>(&Arow[(size_t)m * 1024 + kk + kq]);
            f32x4 xb = *reinterpret_cast<const f32x4*>(&Brow[(size_t)m * 1024 + kk + kq]);
            *reinterpret_cast<f16x4*>(sA + m * 64 + sw) = cvt4h(xa);
            *reinterpret_cast<f16x4*>(sB + m * 64 + sw) = cvt4h(xb);
        }
        __syncthreads();
        f16x8 af[4], bfv[4];
        const int r0 = (w >> 1) * 64, c0 = (w & 1) * 64;
#pragma unroll
        for (int mt = 0; mt < 4; ++mt) {
            int m = r0 + 16 * mt + l15;
            af[mt] = *reinterpret_cast<f16x8*>(sA + m * 64 + ((16 * lg) ^ (((m >> 1) & 3) << 4)));
        }
#pragma unroll
        for (int nt = 0; nt < 4; ++nt) {
            int n = c0 + 16 * nt + l15;
            bfv[nt] = *reinterpret_cast<f16x8*>(sB + n * 64 + ((16 * lg) ^ (((n >> 1) & 3) << 4)));
        }
#pragma unroll
        for (int mt = 0; mt < 4; ++mt)
#pragma unroll
            for (int nt = 0; nt < 4; ++nt)
                acc[mt][nt] = MFMA16H(af[mt], bfv[nt], acc[mt][nt]);
        __syncthreads();
    }
    const int r0 = (w >> 1) * 64, c0 = (w & 1) * 64;
#pragma unroll
    for (int mt = 0; mt < 4; ++mt)
#pragma unroll
        for (int nt = 0; nt < 4; ++nt)
#pragma unroll
            for (int rg = 0; rg < 4; ++rg) {
                int rt = r0 + 16 * mt + 4 * lg + rg;
                int ct = c0 + 16 * nt + l15;
                float v = acc[mt][nt][rg];
                if (kt == qt && ct > rt) v = -30000.f;
                S[((size_t)b * 2048 + qt * 128 + rt) * 2048 + kt * 128 + ct] = (__fp16)v;
            }
}

__global__ __launch_bounds__(512) void pv_gemm_kernel(
    const __fp16* __restrict__ P, const float* __restrict__ enc, float* __restrict__ out)
{
    __shared__ __align__(16) char sA[128 * 128];
    __shared__ __align__(16) char sB[128 * 128];
    const int t = threadIdx.x;
    const int w = t >> 6, l = t & 63;
    const int l15 = l & 15, lg = (l >> 4) & 3;
    const int wq = w >> 2, wdv = w & 3;
    const int qtb = 15 - (int)blockIdx.x;
    const int dblk = blockIdx.y;
    const int b = blockIdx.z;
    const int q0 = 128 * qtb;
    const int nkv = 128 * (qtb + 1);
    const __fp16* Pbase = P + ((size_t)b * 2048 + q0) * 2048;
    const float* Eb = enc + (size_t)b * 2048 * 1024;

    f32x4 acc[4][2];
#pragma unroll
    for (int i = 0; i < 4; ++i)
#pragma unroll
        for (int j = 0; j < 2; ++j) acc[i][j] = (f32x4){0.f, 0.f, 0.f, 0.f};

    const int ar = t >> 2, aseg = t & 3;
    const int ba = t >> 5, bdq = t & 31;

    for (int kv0 = 0; kv0 < nkv; kv0 += 64) {
        __syncthreads();
        {
            const __fp16* src = Pbase + (size_t)ar * 2048 + kv0 + 16 * aseg;
            u32x4 v0 = *reinterpret_cast<const u32x4*>(src);
            u32x4 v1 = *reinterpret_cast<const u32x4*>(src + 8);
            const int sw = (ar & 7) << 4;
            *reinterpret_cast<u32x4*>(sA + ar * 128 + ((32 * aseg) ^ sw)) = v0;
            *reinterpret_cast<u32x4*>(sA + ar * 128 + ((32 * aseg + 16) ^ sw)) = v1;
        }
        {
            const float* src = Eb + (size_t)(kv0 + 4 * ba) * 1024 + 128 * dblk + 4 * bdq;
            f32x4 x0 = *reinterpret_cast<const f32x4*>(src);
            f32x4 x1 = *reinterpret_cast<const f32x4*>(src + 1024);
            f32x4 x2 = *reinterpret_cast<const f32x4*>(src + 2048);
            f32x4 x3 = *reinterpret_cast<const f32x4*>(src + 3072);
#pragma unroll
            for (int j = 0; j < 4; ++j) {
                int d = 4 * bdq + j;
                union { f16x4 v; f16x2 h[2]; } s;
                s.h[0] = __builtin_amdgcn_cvt_pkrtz(x0[j], x1[j]);
                s.h[1] = __builtin_amdgcn_cvt_pkrtz(x2[j], x3[j]);
                *reinterpret_cast<f16x4*>(sB + d * 128 + ((8 * ba) ^ ((d & 7) << 4))) = s.v;
            }
        }
        __syncthreads();
#pragma unroll
        for (int ks = 0; ks < 2; ++ks) {
            f16x8 afr[4], bfr[2];
#pragma unroll
            for (int mt = 0; mt < 4; ++mt) {
                int rr = 64 * wq + 16 * mt + l15;
                afr[mt] = *reinterpret_cast<f16x8*>(sA + rr * 128 + ((64 * ks + 16 * lg) ^ ((rr & 7) << 4)));
            }
#pragma unroll
            for (int nt = 0; nt < 2; ++nt) {
                int d = 32 * wdv + 16 * nt + l15;
                bfr[nt] = *reinterpret_cast<f16x8*>(sB + d * 128 + ((64 * ks + 16 * lg) ^ ((d & 7) << 4)));
            }
#pragma unroll
            for (int mt = 0; mt < 4; ++mt)
#pragma unroll
                for (int nt = 0; nt < 2; ++nt)
                    acc[mt][nt] = MFMA16H(afr[mt], bfr[nt], acc[mt][nt]);
        }
    }
#pragma unroll
    for (int mt = 0; mt < 4; ++mt)
#pragma unroll
        for (int nt = 0; nt < 2; ++nt)
#pragma unroll
            for (int rg = 0; rg < 4; ++rg) {
                size_t row = (size_t)b * 2048 + q0 + 64 * wq + 16 * mt + 4 * lg + rg;
                int col = 128 * dblk + 32 * wdv + 16 * nt + l15;
                out[row * 1024 + col] = acc[mt][nt][rg];
            }
}

// ---------------------------------------------------------------------------
extern "C" void kernel_launch(void* const* d_in, const int* in_sizes, int n_in,
                              void* d_out, int out_size, void* d_ws, size_t ws_size,
                              hipStream_t stream)
{
    const float* enc = (const float*)d_in[0];
    const float* R = (const float*)d_in[1];
    float* out = (float*)d_out;
    const size_t MB = 1u << 20;

    if (ws_size >= 98 * MB) {
        __fp16* S = (__fp16*)d_ws;                                  // 64MB
        __fp16* encT = (__fp16*)((char*)d_ws + 64 * MB);            // 32MB
        __fp16* Rt = (__fp16*)((char*)d_ws + 96 * MB);              // 2MB
        __fp16* Qh = (__fp16*)d_out;                                // 32MB
        __fp16* encH = (__fp16*)d_out + (size_t)16384 * 1024;       // 32MB

        transpose_cvt_kernel<<<dim3(32, 16, 8), 256, 0, stream>>>(enc, encT, encH, 2048, 1024);
        transpose_cvt_kernel<<<dim3(16, 16, 1), 256, 0, stream>>>(R, Rt, (__fp16*)nullptr, 1024, 1024);
        gemm_qr<<<dim3(1024), 256, 0, stream>>>(encH, Rt, Qh);
        gemm_s<<<dim3(1088), 256, 0, stream>>>(Qh, encH, S);
        softmax_kernel<<<dim3(512, 8), 256, 0, stream>>>(S);
        gemm_pv<<<dim3(1024), 256, 0, stream>>>(S, encT, out);
    } else {
        __fp16* S = (__fp16*)d_ws;
        qr_gemm_kernel<<<dim3(128, 8), 256, 0, stream>>>(enc, R, out);
        s_gemm_kernel<<<dim3(136, 8), 256, 0, stream>>>(out, enc, S);
        softmax_kernel<<<dim3(512, 8), 256, 0, stream>>>(S);
        pv_gemm_kernel<<<dim3(16, 8, 8), 512, 0, stream>>>(S, enc, out);
    }
}

// Round 9
// 196.295 us; speedup vs baseline: 1.0158x; 1.0158x over previous
//
#include <hip/hip_runtime.h>
#include <hip/hip_bf16.h>

// RelationAttn: out = softmax_causal((enc @ R) @ enc^T) @ enc
// enc: [8,2048,1024] f32, R: [1024,1024] f32, out: [8,2048,1024] f32
//
// f16 pipeline; GEMM core = m97 staging + T2 swizzle + R9: true T3+T4
// (double-buffer, counted s_waitcnt vmcnt(8) across raw barriers — prefetch
// loads stay in flight; never drain vmcnt to 0 in the main loop).
//   P0: enc -> enc_h (f16, d_out upper 32MB) + enc_t (f16 transposed, ws)
//   P1: R   -> R_t (f16 transposed, ws)
//   K1: Q_h = enc_h @ R_t^T      -> d_out lower 32MB (f16)
//   K2: S = Q_h @ enc_h^T causal -> ws (f16, lower-tri 128^2 tiles)
//   K3: P = softmax_row(S) in place
//   K4: out = P @ enc_t^T        -> d_out (f32, overwrites Q_h/enc_h)
// Fallback (ws < 98MB): R5 pipeline (f32-staged GEMMs).

typedef __attribute__((ext_vector_type(4))) float f32x4;
typedef __attribute__((ext_vector_type(4))) unsigned u32x4;
typedef __attribute__((ext_vector_type(8))) __fp16 f16x8;
typedef __attribute__((ext_vector_type(4))) __fp16 f16x4;
typedef __attribute__((ext_vector_type(2))) __fp16 f16x2;

#define MFMA16H(A, B, C) __builtin_amdgcn_mfma_f32_16x16x32_f16(A, B, C, 0, 0, 0)

__device__ __forceinline__ f16x4 cvt4h(f32x4 a) {
    union { f16x4 v; f16x2 h[2]; } r;
    r.h[0] = __builtin_amdgcn_cvt_pkrtz(a[0], a[1]);
    r.h[1] = __builtin_amdgcn_cvt_pkrtz(a[2], a[3]);
    return r.v;
}

// async global->LDS, 16B per lane; lds dest = wave-uniform base + lane*16
__device__ __forceinline__ void gload16(const void* g, void* l) {
    __builtin_amdgcn_global_load_lds(
        (const __attribute__((address_space(1))) unsigned*)g,
        (__attribute__((address_space(3))) unsigned*)l, 16, 0, 0);
}

// ---------------------------------------------------------------------------
// P0/P1: transpose + convert. src f32 [bz][R][C] -> dstT f16 [bz][C][R]
// and (if dstH) dstH f16 [bz][R][C]. 64x64 tiles, swizzled LDS.
// ---------------------------------------------------------------------------
__global__ __launch_bounds__(256) void transpose_cvt_kernel(
    const float* __restrict__ src, __fp16* __restrict__ dstT,
    __fp16* __restrict__ dstH, int R, int C)
{
    __shared__ __align__(16) char lt[64 * 128];  // [r][c] f16, XOR-swizzled
    const int t = threadIdx.x;
    const int bz = blockIdx.z;
    const int r0 = blockIdx.x * 64, c0 = blockIdx.y * 64;
    const size_t so = (size_t)bz * R * C;
    const int tr = t >> 4;
    const int tc4 = (t & 15) * 4;
#pragma unroll
    for (int p = 0; p < 4; ++p) {
        int rl = tr + 16 * p;
        f32x4 x = *(const f32x4*)(src + so + (size_t)(r0 + rl) * C + c0 + tc4);
        f16x4 h = cvt4h(x);
        if (dstH) *(f16x4*)(dstH + so + (size_t)(r0 + rl) * C + c0 + tc4) = h;
        *(f16x4*)(lt + rl * 128 + ((tc4 * 2) ^ ((rl & 7) << 4))) = h;
    }
    __syncthreads();
#pragma unroll
    for (int p = 0; p < 4; ++p) {
        int dl = tr + 16 * p;
#pragma unroll
        for (int j = 0; j < 4; ++j) {
            int kl = (t & 15) + 16 * j;
            __fp16 v = *(const __fp16*)(lt + kl * 128 + ((dl * 2) ^ ((kl & 7) << 4)));
            dstT[so + (size_t)(c0 + dl) * R + r0 + kl] = v;
        }
    }
}

// ---------------------------------------------------------------------------
// Unified f16 GEMM core: C(128x128) = A(128xK) @ B(128xK)^T.
// Double-buffered LDS; stage(t+1) -> vmcnt(8) -> barrier -> compute(t) ->
// barrier. The 8 prefetch loads stay in flight across the barrier (T4).
// CMODE: 0 = f16 out; 1 = f16 out + causal diag mask; 2 = f32 out.
// ---------------------------------------------------------------------------
template <int CMODE>
__device__ __forceinline__ void gemm_core(
    const __fp16* __restrict__ A, const __fp16* __restrict__ B,
    char* __restrict__ Cptr, int ldA, int ldB, int ldC, int K, bool diag)
{
    __shared__ __align__(16) char sA[2][128 * 128];  // 2 x (128 rows x 64 f16)
    __shared__ __align__(16) char sB[2][128 * 128];
    const int t = threadIdx.x;
    const int w = t >> 6, l = t & 63;
    const int l15 = l & 15, lg = l >> 4;
    const int r0 = (w >> 1) * 64, c0 = (w & 1) * 64;
    const int swz = (l15 & 7) << 4;   // read-side XOR (row&7 == l15&7)

    f32x4 acc[4][4];
#pragma unroll
    for (int i = 0; i < 4; ++i)
#pragma unroll
        for (int j = 0; j < 4; ++j) acc[i][j] = (f32x4){0.f, 0.f, 0.f, 0.f};

    // staging: wave w rows 32w..32w+31; instr i rows 32w+8i..+7;
    // lane l: row += l>>3, SOURCE granule (l&7)^(l>>3) (inverse swizzle).
    const int strow = 32 * w + (l >> 3);
    const int gsrc = (((l & 7) ^ (l >> 3)) << 3);  // element offset (x8 f16)
    const __fp16* pa = A + (size_t)strow * ldA + gsrc;
    const __fp16* pb = B + (size_t)strow * ldB + gsrc;

    const int nt = K >> 6;
    // prologue: stage tile 0 into buffer 0 (8 loads in flight)
#pragma unroll
    for (int i = 0; i < 4; ++i) {
        gload16(pa + (size_t)(8 * i) * ldA, sA[0] + w * 4096 + i * 1024);
        gload16(pb + (size_t)(8 * i) * ldB, sB[0] + w * 4096 + i * 1024);
    }

    for (int tt = 0; tt < nt; ++tt) {
        const int cur = tt & 1;
        if (tt + 1 < nt) {
            // issue next tile's 8 loads, then wait until only those 8 remain:
            // current tile's loads have landed. Prefetch crosses the barrier.
            const int kk = 64 * (tt + 1);
#pragma unroll
            for (int i = 0; i < 4; ++i) {
                gload16(pa + (size_t)(8 * i) * ldA + kk, sA[cur ^ 1] + w * 4096 + i * 1024);
                gload16(pb + (size_t)(8 * i) * ldB + kk, sB[cur ^ 1] + w * 4096 + i * 1024);
            }
            asm volatile("s_waitcnt vmcnt(8)" ::: "memory");
        } else {
            asm volatile("s_waitcnt vmcnt(0)" ::: "memory");
        }
        __builtin_amdgcn_s_barrier();          // all waves' current tile visible
        __builtin_amdgcn_sched_barrier(0);     // don't hoist ds_reads above
        // compute current tile
#pragma unroll
        for (int ks = 0; ks < 2; ++ks) {
            f16x8 af[4], bf[4];
#pragma unroll
            for (int mt = 0; mt < 4; ++mt)
                af[mt] = *(const f16x8*)(sA[cur] + (r0 + 16 * mt + l15) * 128 + ((64 * ks + 16 * lg) ^ swz));
#pragma unroll
            for (int nt2 = 0; nt2 < 4; ++nt2)
                bf[nt2] = *(const f16x8*)(sB[cur] + (c0 + 16 * nt2 + l15) * 128 + ((64 * ks + 16 * lg) ^ swz));
#pragma unroll
            for (int mt = 0; mt < 4; ++mt)
#pragma unroll
                for (int nt2 = 0; nt2 < 4; ++nt2)
                    acc[mt][nt2] = MFMA16H(af[mt], bf[nt2], acc[mt][nt2]);
        }
        __builtin_amdgcn_sched_barrier(0);     // don't sink ds_reads below
        __builtin_amdgcn_s_barrier();          // readers done -> buf reusable
    }
    // C/D layout: col = l15, row = 4*lg + rg
#pragma unroll
    for (int mt = 0; mt < 4; ++mt)
#pragma unroll
        for (int nt2 = 0; nt2 < 4; ++nt2)
#pragma unroll
            for (int rg = 0; rg < 4; ++rg) {
                int rr = r0 + 16 * mt + 4 * lg + rg;
                int cc = c0 + 16 * nt2 + l15;
                float v = acc[mt][nt2][rg];
                if (CMODE == 2) {
                    *(float*)(Cptr + ((size_t)rr * ldC + cc) * 4) = v;
                } else {
                    if (CMODE == 1 && diag && cc > rr) v = -30000.f;
                    *(__fp16*)(Cptr + ((size_t)rr * ldC + cc) * 2) = (__fp16)v;
                }
            }
}

// K1: Q_h = enc_h @ R_t^T  (16384x1024 @ 1024x1024)
__global__ __launch_bounds__(256) void gemm_qr(
    const __fp16* __restrict__ encH, const __fp16* __restrict__ Rt,
    __fp16* __restrict__ Qh)
{
    const int bm = ((int)blockIdx.x >> 3) * 128;
    const int bn = ((int)blockIdx.x & 7) * 128;
    gemm_core<0>(encH + (size_t)bm * 1024, Rt + (size_t)bn * 1024,
                 (char*)(Qh + (size_t)bm * 1024 + bn), 1024, 1024, 1024, 1024, false);
}

// K2: S = Q_h @ enc_h^T, causal lower-tri tiles. batch = bid&7 (XCD affinity).
__global__ __launch_bounds__(256) void gemm_s(
    const __fp16* __restrict__ Qh, const __fp16* __restrict__ encH,
    __fp16* __restrict__ S)
{
    const int b = (int)blockIdx.x & 7;
    int rem = 135 - ((int)blockIdx.x >> 3);
    int qt = 0;
    while (rem > qt) { rem -= qt + 1; ++qt; }
    const int kt = rem;
    const size_t bo = (size_t)b * 2048 * 1024;
    const size_t so = (size_t)b * 2048 * 2048;
    gemm_core<1>(Qh + bo + (size_t)(qt * 128) * 1024,
                 encH + bo + (size_t)(kt * 128) * 1024,
                 (char*)(S + so + (size_t)(qt * 128) * 2048 + kt * 128),
                 1024, 1024, 2048, 1024, qt == kt);
}

// K4: out = P @ enc_t^T. Variable K = 128*(qtb+1), heavy-first.
__global__ __launch_bounds__(256) void gemm_pv(
    const __fp16* __restrict__ P, const __fp16* __restrict__ encT,
    float* __restrict__ out)
{
    const int b = (int)blockIdx.x & 7;
    const int r = (int)blockIdx.x >> 3;      // 0..127
    const int qtb = 15 - (r >> 3);
    const int dblk = r & 7;
    const size_t so = (size_t)b * 2048 * 2048;
    const size_t to = (size_t)b * 1024 * 2048;
    const int K = 128 * (qtb + 1);
    gemm_core<2>(P + so + (size_t)(qtb * 128) * 2048,
                 encT + to + (size_t)(dblk * 128) * 2048,
                 (char*)(out + (size_t)b * 2048 * 1024 + (size_t)(qtb * 128) * 1024 + dblk * 128),
                 2048, 2048, 1024, K, false);
}

// ---------------------------------------------------------------------------
// K3: in-place row softmax over S (f16). One wave per row; L = roundup(r+1,128).
// ---------------------------------------------------------------------------
__global__ __launch_bounds__(256) void softmax_kernel(__fp16* __restrict__ S)
{
    const int t = threadIdx.x;
    const int wv = t >> 6, l = t & 63;
    const int r = blockIdx.x * 4 + wv;
    const int b = blockIdx.y;
    __fp16* row = S + ((size_t)b * 2048 + r) * 2048;
    const int L = ((r >> 7) + 1) << 7;

    float v[4][8];
    float mx = -1e30f;
#pragma unroll
    for (int i = 0; i < 4; ++i) {
        int c0 = 8 * l + 512 * i;
        if (c0 < L) {
            f16x8 h = *reinterpret_cast<const f16x8*>(row + c0);
#pragma unroll
            for (int j = 0; j < 8; ++j) { v[i][j] = (float)h[j]; mx = fmaxf(mx, v[i][j]); }
        } else {
#pragma unroll
            for (int j = 0; j < 8; ++j) v[i][j] = -1e30f;
        }
    }
#pragma unroll
    for (int off = 1; off < 64; off <<= 1) mx = fmaxf(mx, __shfl_xor(mx, off));
    float sm = 0.f;
#pragma unroll
    for (int i = 0; i < 4; ++i)
#pragma unroll
        for (int j = 0; j < 8; ++j) { v[i][j] = __expf(v[i][j] - mx); sm += v[i][j]; }
#pragma unroll
    for (int off = 1; off < 64; off <<= 1) sm += __shfl_xor(sm, off);
    const float inv = 1.f / sm;
#pragma unroll
    for (int i = 0; i < 4; ++i) {
        int c0 = 8 * l + 512 * i;
        if (c0 < L) {
            union { f16x8 v8; f16x2 h[4]; } o;
#pragma unroll
            for (int j = 0; j < 4; ++j)
                o.h[j] = __builtin_amdgcn_cvt_pkrtz(v[i][2 * j] * inv, v[i][2 * j + 1] * inv);
            *reinterpret_cast<f16x8*>(row + c0) = o.v8;
        }
    }
}

// ===========================================================================
// Fallback path (R5): f32-staged GEMMs, used only if ws < 98MB.
// ===========================================================================
__global__ __launch_bounds__(256) void qr_gemm_kernel(
    const float* __restrict__ A, const float* __restrict__ B, float* C)
{
    __shared__ __align__(16) char sA[128 * 64];
    __shared__ __align__(16) char sB[128 * 64];
    const int t = threadIdx.x;
    const int w = t >> 6, l = t & 63;
    const int l15 = l & 15, lg = l >> 4;
    const int bm = blockIdx.x * 128;
    const int bn = blockIdx.y * 128;

    f32x4 acc[4][4];
#pragma unroll
    for (int i = 0; i < 4; ++i)
#pragma unroll
        for (int j = 0; j < 4; ++j) acc[i][j] = (f32x4){0.f, 0.f, 0.f, 0.f};

    const int kq = 4 * (t & 7);
    const int i2 = t >> 3;

    for (int kk = 0; kk < 1024; kk += 32) {
#pragma unroll
        for (int it = 0; it < 4; ++it) {
            int m = i2 + 32 * it;
            f32x4 x = *reinterpret_cast<const f32x4*>(&A[(size_t)(bm + m) * 1024 + kk + kq]);
            *reinterpret_cast<f16x4*>(sA + m * 64 + ((2 * kq) ^ (((m >> 1) & 3) << 4))) = cvt4h(x);
        }
        {
            int n0 = 4 * i2;
            f32x4 x[4];
#pragma unroll
            for (int r = 0; r < 4; ++r)
                x[r] = *reinterpret_cast<const f32x4*>(&B[(size_t)(kk + kq + r) * 1024 + bn + n0]);
#pragma unroll
            for (int j = 0; j < 4; ++j) {
                int n = n0 + j;
                union { f16x4 v; f16x2 h[2]; } s;
                s.h[0] = __builtin_amdgcn_cvt_pkrtz(x[0][j], x[1][j]);
                s.h[1] = __builtin_amdgcn_cvt_pkrtz(x[2][j], x[3][j]);
                *reinterpret_cast<f16x4*>(sB + n * 64 + ((2 * kq) ^ (((n >> 1) & 3) << 4))) = s.v;
            }
        }
        __syncthreads();
        f16x8 af[4], bfv[4];
        const int r0 = (w >> 1) * 64, c0 = (w & 1) * 64;
#pragma unroll
        for (int mt = 0; mt < 4; ++mt) {
            int m = r0 + 16 * mt + l15;
            af[mt] = *reinterpret_cast<f16x8*>(sA + m * 64 + ((16 * lg) ^ (((m >> 1) & 3) << 4)));
        }
#pragma unroll
        for (int nt = 0; nt < 4; ++nt) {
            int n = c0 + 16 * nt + l15;
            bfv[nt] = *reinterpret_cast<f16x8*>(sB + n * 64 + ((16 * lg) ^ (((n >> 1) & 3) << 4)));
        }
#pragma unroll
        for (int mt = 0; mt < 4; ++mt)
#pragma unroll
            for (int nt = 0; nt < 4; ++nt)
                acc[mt][nt] = MFMA16H(af[mt], bfv[nt], acc[mt][nt]);
        __syncthreads();
    }
#pragma unroll
    for (int mt = 0; mt < 4; ++mt)
#pragma unroll
        for (int nt = 0; nt < 4; ++nt)
#pragma unroll
            for (int rg = 0; rg < 4; ++rg) {
                int row = bm + (w >> 1) * 64 + 16 * mt + 4 * lg + rg;
                int col = bn + (w & 1) * 64 + 16 * nt + l15;
                C[(size_t)row * 1024 + col] = acc[mt][nt][rg];
            }
}

__global__ __launch_bounds__(256) void s_gemm_kernel(
    const float* __restrict__ Q, const float* __restrict__ enc, __fp16* __restrict__ S)
{
    __shared__ __align__(16) char sA[128 * 64];
    __shared__ __align__(16) char sB[128 * 64];
    const int t = threadIdx.x;
    const int w = t >> 6, l = t & 63;
    const int l15 = l & 15, lg = l >> 4;

    int rem = 135 - (int)blockIdx.x;
    int qt = 0;
    while (rem > qt) { rem -= qt + 1; ++qt; }
    const int kt = rem;
    const int b = blockIdx.y;
    const float* Arow = Q + ((size_t)b * 2048 + qt * 128) * 1024;
    const float* Brow = enc + ((size_t)b * 2048 + kt * 128) * 1024;

    f32x4 acc[4][4];
#pragma unroll
    for (int i = 0; i < 4; ++i)
#pragma unroll
        for (int j = 0; j < 4; ++j) acc[i][j] = (f32x4){0.f, 0.f, 0.f, 0.f};

    const int kq = 4 * (t & 7);
    const int i2 = t >> 3;

    for (int kk = 0; kk < 1024; kk += 32) {
#pragma unroll
        for (int it = 0; it < 4; ++it) {
            int m = i2 + 32 * it;
            int sw = (2 * kq) ^ (((m >> 1) & 3) << 4);
            f32x4 xa = *reinterpret_cast<const f32x4*>(&Arow[(size_t)m * 1024 + kk + kq]);
            f32x4 xb = *reinterpret_cast<const f32x4*>(&Brow[(size_t)m * 1024 + kk + kq]);
            *reinterpret_cast<f16x4*>(sA + m * 64 + sw) = cvt4h(xa);
            *reinterpret_cast<f16x4*>(sB + m * 64 + sw) = cvt4h(xb);
        }
        __syncthreads();
        f16x8 af[4], bfv[4];
        const int r0 = (w >> 1) * 64, c0 = (w & 1) * 64;
#pragma unroll
        for (int mt = 0; mt < 4; ++mt) {
            int m = r0 + 16 * mt + l15;
            af[mt] = *reinterpret_cast<f16x8*>(sA + m * 64 + ((16 * lg) ^ (((m >> 1) & 3) << 4)));
        }
#pragma unroll
        for (int nt = 0; nt < 4; ++nt) {
            int n = c0 + 16 * nt + l15;
            bfv[nt] = *reinterpret_cast<f16x8*>(sB + n * 64 + ((16 * lg) ^ (((n >> 1) & 3) << 4)));
        }
#pragma unroll
        for (int mt = 0; mt < 4; ++mt)
#pragma unroll
            for (int nt = 0; nt < 4; ++nt)
                acc[mt][nt] = MFMA16H(af[mt], bfv[nt], acc[mt][nt]);
        __syncthreads();
    }
    const int r0 = (w >> 1) * 64, c0 = (w & 1) * 64;
#pragma unroll
    for (int mt = 0; mt < 4; ++mt)
#pragma unroll
        for (int nt = 0; nt < 4; ++nt)
#pragma unroll
            for (int rg = 0; rg < 4; ++rg) {
                int rt = r0 + 16 * mt + 4 * lg + rg;
                int ct = c0 + 16 * nt + l15;
                float v = acc[mt][nt][rg];
                if (kt == qt && ct > rt) v = -30000.f;
                S[((size_t)b * 2048 + qt * 128 + rt) * 2048 + kt * 128 + ct] = (__fp16)v;
            }
}

__global__ __launch_bounds__(512) void pv_gemm_kernel(
    const __fp16* __restrict__ P, const float* __restrict__ enc, float* __restrict__ out)
{
    __shared__ __align__(16) char sA[128 * 128];
    __shared__ __align__(16) char sB[128 * 128];
    const int t = threadIdx.x;
    const int w = t >> 6, l = t & 63;
    const int l15 = l & 15, lg = (l >> 4) & 3;
    const int wq = w >> 2, wdv = w & 3;
    const int qtb = 15 - (int)blockIdx.x;
    const int dblk = blockIdx.y;
    const int b = blockIdx.z;
    const int q0 = 128 * qtb;
    const int nkv = 128 * (qtb + 1);
    const __fp16* Pbase = P + ((size_t)b * 2048 + q0) * 2048;
    const float* Eb = enc + (size_t)b * 2048 * 1024;

    f32x4 acc[4][2];
#pragma unroll
    for (int i = 0; i < 4; ++i)
#pragma unroll
        for (int j = 0; j < 2; ++j) acc[i][j] = (f32x4){0.f, 0.f, 0.f, 0.f};

    const int ar = t >> 2, aseg = t & 3;
    const int ba = t >> 5, bdq = t & 31;

    for (int kv0 = 0; kv0 < nkv; kv0 += 64) {
        __syncthreads();
        {
            const __fp16* src = Pbase + (size_t)ar * 2048 + kv0 + 16 * aseg;
            u32x4 v0 = *reinterpret_cast<const u32x4*>(src);
            u32x4 v1 = *reinterpret_cast<const u32x4*>(src + 8);
            const int sw = (ar & 7) << 4;
            *reinterpret_cast<u32x4*>(sA + ar * 128 + ((32 * aseg) ^ sw)) = v0;
            *reinterpret_cast<u32x4*>(sA + ar * 128 + ((32 * aseg + 16) ^ sw)) = v1;
        }
        {
            const float* src = Eb + (size_t)(kv0 + 4 * ba) * 1024 + 128 * dblk + 4 * bdq;
            f32x4 x0 = *reinterpret_cast<const f32x4*>(src);
            f32x4 x1 = *reinterpret_cast<const f32x4*>(src + 1024);
            f32x4 x2 = *reinterpret_cast<const f32x4*>(src + 2048);
            f32x4 x3 = *reinterpret_cast<const f32x4*>(src + 3072);
#pragma unroll
            for (int j = 0; j < 4; ++j) {
                int d = 4 * bdq + j;
                union { f16x4 v; f16x2 h[2]; } s;
                s.h[0] = __builtin_amdgcn_cvt_pkrtz(x0[j], x1[j]);
                s.h[1] = __builtin_amdgcn_cvt_pkrtz(x2[j], x3[j]);
                *reinterpret_cast<f16x4*>(sB + d * 128 + ((8 * ba) ^ ((d & 7) << 4))) = s.v;
            }
        }
        __syncthreads();
#pragma unroll
        for (int ks = 0; ks < 2; ++ks) {
            f16x8 afr[4], bfr[2];
#pragma unroll
            for (int mt = 0; mt < 4; ++mt) {
                int rr = 64 * wq + 16 * mt + l15;
                afr[mt] = *reinterpret_cast<f16x8*>(sA + rr * 128 + ((64 * ks + 16 * lg) ^ ((rr & 7) << 4)));
            }
#pragma unroll
            for (int nt = 0; nt < 2; ++nt) {
                int d = 32 * wdv + 16 * nt + l15;
                bfr[nt] = *reinterpret_cast<f16x8*>(sB + d * 128 + ((64 * ks + 16 * lg) ^ ((d & 7) << 4)));
            }
#pragma unroll
            for (int mt = 0; mt < 4; ++mt)
#pragma unroll
                for (int nt = 0; nt < 2; ++nt)
                    acc[mt][nt] = MFMA16H(afr[mt], bfr[nt], acc[mt][nt]);
        }
    }
#pragma unroll
    for (int mt = 0; mt < 4; ++mt)
#pragma unroll
        for (int nt = 0; nt < 2; ++nt)
#pragma unroll
            for (int rg = 0; rg < 4; ++rg) {
                size_t row = (size_t)b * 2048 + q0 + 64 * wq + 16 * mt + 4 * lg + rg;
                int col = 128 * dblk + 32 * wdv + 16 * nt + l15;
                out[row * 1024 + col] = acc[mt][nt][rg];
            }
}

// ---------------------------------------------------------------------------
extern "C" void kernel_launch(void* const* d_in, const int* in_sizes, int n_in,
                              void* d_out, int out_size, void* d_ws, size_t ws_size,
                              hipStream_t stream)
{
    const float* enc = (const float*)d_in[0];
    const float* R = (const float*)d_in[1];
    float* out = (float*)d_out;
    const size_t MB = 1u << 20;

    if (ws_size >= 98 * MB) {
        __fp16* S = (__fp16*)d_ws;                                  // 64MB
        __fp16* encT = (__fp16*)((char*)d_ws + 64 * MB);            // 32MB
        __fp16* Rt = (__fp16*)((char*)d_ws + 96 * MB);              // 2MB
        __fp16* Qh = (__fp16*)d_out;                                // 32MB
        __fp16* encH = (__fp16*)d_out + (size_t)16384 * 1024;       // 32MB

        transpose_cvt_kernel<<<dim3(32, 16, 8), 256, 0, stream>>>(enc, encT, encH, 2048, 1024);
        transpose_cvt_kernel<<<dim3(16, 16, 1), 256, 0, stream>>>(R, Rt, (__fp16*)nullptr, 1024, 1024);
        gemm_qr<<<dim3(1024), 256, 0, stream>>>(encH, Rt, Qh);
        gemm_s<<<dim3(1088), 256, 0, stream>>>(Qh, encH, S);
        softmax_kernel<<<dim3(512, 8), 256, 0, stream>>>(S);
        gemm_pv<<<dim3(1024), 256, 0, stream>>>(S, encT, out);
    } else {
        __fp16* S = (__fp16*)d_ws;
        qr_gemm_kernel<<<dim3(128, 8), 256, 0, stream>>>(enc, R, out);
        s_gemm_kernel<<<dim3(136, 8), 256, 0, stream>>>(out, enc, S);
        softmax_kernel<<<dim3(512, 8), 256, 0, stream>>>(S);
        pv_gemm_kernel<<<dim3(16, 8, 8), 512, 0, stream>>>(S, enc, out);
    }
}

// Round 10
// 183.292 us; speedup vs baseline: 1.0879x; 1.0709x over previous
//
#include <hip/hip_runtime.h>
#include <hip/hip_bf16.h>

// RelationAttn: out = softmax_causal((enc @ R) @ enc^T) @ enc
// enc: [8,2048,1024] f32, R: [1024,1024] f32, out: [8,2048,1024] f32
//
// R10: gemm_qr -> 8-phase 256^2 template (T3+T4+T5, counted vmcnt, 128KB LDS,
//      1 block/CU, zero imbalance). gemm_s / gemm_pv back to the proven R7
//      single-buffer core (68.5us gemm_s).
//   P0: enc -> enc_h (f16) + enc_t (f16 transposed)
//   P1: R   -> R_t
//   K1: Q_h = enc_h @ R_t^T      (8-phase 256^2)
//   K2: S = Q_h @ enc_h^T causal (R7 core, 128^2)
//   K3: P = softmax_row(S)
//   K4: out = P @ enc_t^T        (R7 core)
// Fallback (ws < 98MB): R5 pipeline.

typedef __attribute__((ext_vector_type(4))) float f32x4;
typedef __attribute__((ext_vector_type(4))) unsigned u32x4;
typedef __attribute__((ext_vector_type(8))) __fp16 f16x8;
typedef __attribute__((ext_vector_type(4))) __fp16 f16x4;
typedef __attribute__((ext_vector_type(2))) __fp16 f16x2;

#define MFMA16H(A, B, C) __builtin_amdgcn_mfma_f32_16x16x32_f16(A, B, C, 0, 0, 0)

__device__ __forceinline__ f16x4 cvt4h(f32x4 a) {
    union { f16x4 v; f16x2 h[2]; } r;
    r.h[0] = __builtin_amdgcn_cvt_pkrtz(a[0], a[1]);
    r.h[1] = __builtin_amdgcn_cvt_pkrtz(a[2], a[3]);
    return r.v;
}

__device__ __forceinline__ void gload16(const void* g, void* l) {
    __builtin_amdgcn_global_load_lds(
        (const __attribute__((address_space(1))) unsigned*)g,
        (__attribute__((address_space(3))) unsigned*)l, 16, 0, 0);
}

#define BAR() do { __builtin_amdgcn_sched_barrier(0); \
                   __builtin_amdgcn_s_barrier();      \
                   __builtin_amdgcn_sched_barrier(0); } while (0)

// ---------------------------------------------------------------------------
// P0/P1: transpose + convert (unchanged from R7)
// ---------------------------------------------------------------------------
__global__ __launch_bounds__(256) void transpose_cvt_kernel(
    const float* __restrict__ src, __fp16* __restrict__ dstT,
    __fp16* __restrict__ dstH, int R, int C)
{
    __shared__ __align__(16) char lt[64 * 128];
    const int t = threadIdx.x;
    const int bz = blockIdx.z;
    const int r0 = blockIdx.x * 64, c0 = blockIdx.y * 64;
    const size_t so = (size_t)bz * R * C;
    const int tr = t >> 4;
    const int tc4 = (t & 15) * 4;
#pragma unroll
    for (int p = 0; p < 4; ++p) {
        int rl = tr + 16 * p;
        f32x4 x = *(const f32x4*)(src + so + (size_t)(r0 + rl) * C + c0 + tc4);
        f16x4 h = cvt4h(x);
        if (dstH) *(f16x4*)(dstH + so + (size_t)(r0 + rl) * C + c0 + tc4) = h;
        *(f16x4*)(lt + rl * 128 + ((tc4 * 2) ^ ((rl & 7) << 4))) = h;
    }
    __syncthreads();
#pragma unroll
    for (int p = 0; p < 4; ++p) {
        int dl = tr + 16 * p;
#pragma unroll
        for (int j = 0; j < 4; ++j) {
            int kl = (t & 15) + 16 * j;
            __fp16 v = *(const __fp16*)(lt + kl * 128 + ((dl * 2) ^ ((kl & 7) << 4)));
            dstT[so + (size_t)(c0 + dl) * R + r0 + kl] = v;
        }
    }
}

// ---------------------------------------------------------------------------
// K1: 8-phase 256^2 GEMM. Q_h(16384x1024) = encH @ Rt^T. 256 blocks (1/CU),
// 512 thr / 8 waves (2Mx4N, per-wave 128x64 output). K=1024 -> 8 iterations,
// 2 K-tiles (BK=64) per iteration, 8 phases. LDS 128KB: 2 tile-bufs x {A,B}
// x 2 k-halves of 16KB. k-half layout: [256 rows][4 slots of 16B], slot =
// (lg + (row>>1)) & 3  (2-way banks on read AND write = free).
// Region protocol: each k-half region is re-staged exactly one phase after
// its last ds_read; counted vmcnt(8) at odd phases keeps 4 half-tile loads
// in flight across barriers (tail: 8/8/4/0).
// ---------------------------------------------------------------------------
__global__ __launch_bounds__(512, 2) void gemm_qr256(
    const __fp16* __restrict__ encH, const __fp16* __restrict__ Rt,
    __fp16* __restrict__ Qh)
{
    __shared__ __align__(16) char lds[131072];
    const int t = threadIdx.x;
    const int w = t >> 6, l = t & 63;
    const int l15 = l & 15, lg = (l >> 4) & 3;
    const int wr = w >> 2, wc = w & 3;
    const int bm = ((int)blockIdx.x >> 2) * 256;
    const int bn = ((int)blockIdx.x & 3) * 256;
    const __fp16* Ag = encH + (size_t)bm * 1024;
    const __fp16* Bg = Rt + (size_t)bn * 1024;

    const int srow = 32 * w + (l >> 2);                  // staging row
    const int slg = ((l & 3) - ((l >> 3) & 3)) & 3;      // staging logical granule
    const int slotr = ((l >> 4) + ((l & 15) >> 1)) & 3;  // read-side slot

    f32x4 acc[8][4];
#pragma unroll
    for (int i = 0; i < 8; ++i)
#pragma unroll
        for (int j = 0; j < 4; ++j) acc[i][j] = (f32x4){0.f, 0.f, 0.f, 0.f};

    auto stage = [&](int op, int tile, int kh) {
        const __fp16* src = (op ? Bg : Ag) + (size_t)srow * 1024 + tile * 64 + kh * 32 + slg * 8;
        char* dst = lds + (tile & 1) * 65536 + op * 32768 + kh * 16384 + w * 2048;
        gload16(src, dst);
        gload16(src + (size_t)16 * 1024, dst + 1024);
    };
    auto rdA = [&](int buf, int ks, int mf) {
        return *(const f16x8*)(lds + buf * 65536 + ks * 16384
                               + (128 * wr + 16 * mf + l15) * 64 + slotr * 16);
    };
    auto rdB = [&](int buf, int ks, int nf) {
        return *(const f16x8*)(lds + buf * 65536 + 32768 + ks * 16384
                               + (64 * wc + 16 * nf + l15) * 64 + slotr * 16);
    };

    // prologue: tile0 (all 4 halves), tile1 (k0 halves) = 12 gloads/thread
    stage(0, 0, 0); stage(1, 0, 0); stage(0, 0, 1); stage(1, 0, 1);
    stage(0, 1, 0); stage(1, 1, 0);

    f16x8 afr[4], bfr[4];

#define MF16(mbase)                                                     \
    __builtin_amdgcn_s_setprio(1);                                      \
    _Pragma("unroll") for (int mf = 0; mf < 4; ++mf)                    \
        _Pragma("unroll") for (int nf = 0; nf < 4; ++nf)                \
            acc[(mbase) + mf][nf] = MFMA16H(afr[mf], bfr[nf], acc[(mbase) + mf][nf]); \
    __builtin_amdgcn_s_setprio(0);

    for (int i = 0; i < 8; ++i) {
        const bool lastI = (i == 7);
        // ---- P1: tile 2i (buf0) ks0, m0-3; stage Ak1(2i+1)->buf1 ----
        asm volatile("s_waitcnt vmcnt(8)" ::: "memory");
        BAR();
#pragma unroll
        for (int nf = 0; nf < 4; ++nf) bfr[nf] = rdB(0, 0, nf);
#pragma unroll
        for (int mf = 0; mf < 4; ++mf) afr[mf] = rdA(0, 0, mf);
        stage(0, 2 * i + 1, 1);
        MF16(0)
        // ---- P2: ks0, m4-7; stage Bk1(2i+1) ----
        BAR();
#pragma unroll
        for (int mf = 0; mf < 4; ++mf) afr[mf] = rdA(0, 0, mf + 4);
        stage(1, 2 * i + 1, 1);
        MF16(4)
        // ---- P3: ks1, m0-3; stage Ak0(2i+2)->buf0 (Ak0 freed after P2) ----
        asm volatile("s_waitcnt vmcnt(8)" ::: "memory");
        BAR();
#pragma unroll
        for (int nf = 0; nf < 4; ++nf) bfr[nf] = rdB(0, 1, nf);
#pragma unroll
        for (int mf = 0; mf < 4; ++mf) afr[mf] = rdA(0, 1, mf);
        if (!lastI) stage(0, 2 * i + 2, 0);
        MF16(0)
        // ---- P4: ks1, m4-7; stage Bk0(2i+2) ----
        BAR();
#pragma unroll
        for (int mf = 0; mf < 4; ++mf) afr[mf] = rdA(0, 1, mf + 4);
        if (!lastI) stage(1, 2 * i + 2, 0);
        MF16(4)
        // ---- P5: tile 2i+1 (buf1) ks0, m0-3; stage Ak1(2i+2) ----
        if (!lastI) asm volatile("s_waitcnt vmcnt(8)" ::: "memory");
        else        asm volatile("s_waitcnt vmcnt(4)" ::: "memory");
        BAR();
#pragma unroll
        for (int nf = 0; nf < 4; ++nf) bfr[nf] = rdB(1, 0, nf);
#pragma unroll
        for (int mf = 0; mf < 4; ++mf) afr[mf] = rdA(1, 0, mf);
        if (!lastI) stage(0, 2 * i + 2, 1);
        MF16(0)
        // ---- P6: ks0, m4-7; stage Bk1(2i+2) ----
        BAR();
#pragma unroll
        for (int mf = 0; mf < 4; ++mf) afr[mf] = rdA(1, 0, mf + 4);
        if (!lastI) stage(1, 2 * i + 2, 1);
        MF16(4)
        // ---- P7: ks1, m0-3; stage Ak0(2i+3)->buf1 ----
        if (!lastI) asm volatile("s_waitcnt vmcnt(8)" ::: "memory");
        else        asm volatile("s_waitcnt vmcnt(0)" ::: "memory");
        BAR();
#pragma unroll
        for (int nf = 0; nf < 4; ++nf) bfr[nf] = rdB(1, 1, nf);
#pragma unroll
        for (int mf = 0; mf < 4; ++mf) afr[mf] = rdA(1, 1, mf);
        if (!lastI) stage(0, 2 * i + 3, 0);
        MF16(0)
        // ---- P8: ks1, m4-7; stage Bk0(2i+3) ----
        BAR();
#pragma unroll
        for (int mf = 0; mf < 4; ++mf) afr[mf] = rdA(1, 1, mf + 4);
        if (!lastI) stage(1, 2 * i + 3, 0);
        MF16(4)
    }
#undef MF16

    // epilogue: C/D layout col=l15, row=4*lg+rg
#pragma unroll
    for (int mf = 0; mf < 8; ++mf)
#pragma unroll
        for (int nf = 0; nf < 4; ++nf)
#pragma unroll
            for (int rg = 0; rg < 4; ++rg) {
                int rr = bm + 128 * wr + 16 * mf + 4 * lg + rg;
                int cc = bn + 64 * wc + 16 * nf + l15;
                Qh[(size_t)rr * 1024 + cc] = (__fp16)acc[mf][nf][rg];
            }
}

// ---------------------------------------------------------------------------
// R7 GEMM core (proven): single-buffer, 2 barriers/K-step, T2 swizzle.
// CMODE: 0 = f16 out; 1 = f16 + causal diag mask; 2 = f32 out.
// ---------------------------------------------------------------------------
template <int CMODE>
__device__ __forceinline__ void gemm_core(
    const __fp16* __restrict__ A, const __fp16* __restrict__ B,
    char* __restrict__ Cptr, int ldA, int ldB, int ldC, int K, bool diag)
{
    __shared__ __align__(16) char sA[128 * 128];
    __shared__ __align__(16) char sB[128 * 128];
    const int t = threadIdx.x;
    const int w = t >> 6, l = t & 63;
    const int l15 = l & 15, lg = l >> 4;
    const int r0 = (w >> 1) * 64, c0 = (w & 1) * 64;
    const int swz = (l15 & 7) << 4;

    f32x4 acc[4][4];
#pragma unroll
    for (int i = 0; i < 4; ++i)
#pragma unroll
        for (int j = 0; j < 4; ++j) acc[i][j] = (f32x4){0.f, 0.f, 0.f, 0.f};

    const int strow = 32 * w + (l >> 3);
    const int gsrc = (((l & 7) ^ (l >> 3)) << 3);
    const __fp16* pa = A + (size_t)strow * ldA + gsrc;
    const __fp16* pb = B + (size_t)strow * ldB + gsrc;

    for (int kk = 0; kk < K; kk += 64) {
        __syncthreads();
#pragma unroll
        for (int i = 0; i < 4; ++i) {
            gload16(pa + (size_t)(8 * i) * ldA + kk, sA + w * 4096 + i * 1024);
            gload16(pb + (size_t)(8 * i) * ldB + kk, sB + w * 4096 + i * 1024);
        }
        __syncthreads();
#pragma unroll
        for (int ks = 0; ks < 2; ++ks) {
            f16x8 af[4], bf[4];
#pragma unroll
            for (int mt = 0; mt < 4; ++mt)
                af[mt] = *(const f16x8*)(sA + (r0 + 16 * mt + l15) * 128 + ((64 * ks + 16 * lg) ^ swz));
#pragma unroll
            for (int nt = 0; nt < 4; ++nt)
                bf[nt] = *(const f16x8*)(sB + (c0 + 16 * nt + l15) * 128 + ((64 * ks + 16 * lg) ^ swz));
#pragma unroll
            for (int mt = 0; mt < 4; ++mt)
#pragma unroll
                for (int nt = 0; nt < 4; ++nt)
                    acc[mt][nt] = MFMA16H(af[mt], bf[nt], acc[mt][nt]);
        }
    }
#pragma unroll
    for (int mt = 0; mt < 4; ++mt)
#pragma unroll
        for (int nt = 0; nt < 4; ++nt)
#pragma unroll
            for (int rg = 0; rg < 4; ++rg) {
                int rr = r0 + 16 * mt + 4 * lg + rg;
                int cc = c0 + 16 * nt + l15;
                float v = acc[mt][nt][rg];
                if (CMODE == 2) {
                    *(float*)(Cptr + ((size_t)rr * ldC + cc) * 4) = v;
                } else {
                    if (CMODE == 1 && diag && cc > rr) v = -30000.f;
                    *(__fp16*)(Cptr + ((size_t)rr * ldC + cc) * 2) = (__fp16)v;
                }
            }
}

// K2: S = Q_h @ enc_h^T, causal lower-tri tiles.
__global__ __launch_bounds__(256) void gemm_s(
    const __fp16* __restrict__ Qh, const __fp16* __restrict__ encH,
    __fp16* __restrict__ S)
{
    const int b = (int)blockIdx.x & 7;
    int rem = 135 - ((int)blockIdx.x >> 3);
    int qt = 0;
    while (rem > qt) { rem -= qt + 1; ++qt; }
    const int kt = rem;
    const size_t bo = (size_t)b * 2048 * 1024;
    const size_t so = (size_t)b * 2048 * 2048;
    gemm_core<1>(Qh + bo + (size_t)(qt * 128) * 1024,
                 encH + bo + (size_t)(kt * 128) * 1024,
                 (char*)(S + so + (size_t)(qt * 128) * 2048 + kt * 128),
                 1024, 1024, 2048, 1024, qt == kt);
}

// K4: out = P @ enc_t^T.
__global__ __launch_bounds__(256) void gemm_pv(
    const __fp16* __restrict__ P, const __fp16* __restrict__ encT,
    float* __restrict__ out)
{
    const int b = (int)blockIdx.x & 7;
    const int r = (int)blockIdx.x >> 3;
    const int qtb = 15 - (r >> 3);
    const int dblk = r & 7;
    const size_t so = (size_t)b * 2048 * 2048;
    const size_t to = (size_t)b * 1024 * 2048;
    const int K = 128 * (qtb + 1);
    gemm_core<2>(P + so + (size_t)(qtb * 128) * 2048,
                 encT + to + (size_t)(dblk * 128) * 2048,
                 (char*)(out + (size_t)b * 2048 * 1024 + (size_t)(qtb * 128) * 1024 + dblk * 128),
                 2048, 2048, 1024, K, false);
}

// ---------------------------------------------------------------------------
// K3: in-place row softmax over S (f16).
// ---------------------------------------------------------------------------
__global__ __launch_bounds__(256) void softmax_kernel(__fp16* __restrict__ S)
{
    const int t = threadIdx.x;
    const int wv = t >> 6, l = t & 63;
    const int r = blockIdx.x * 4 + wv;
    const int b = blockIdx.y;
    __fp16* row = S + ((size_t)b * 2048 + r) * 2048;
    const int L = ((r >> 7) + 1) << 7;

    float v[4][8];
    float mx = -1e30f;
#pragma unroll
    for (int i = 0; i < 4; ++i) {
        int c0 = 8 * l + 512 * i;
        if (c0 < L) {
            f16x8 h = *reinterpret_cast<const f16x8*>(row + c0);
#pragma unroll
            for (int j = 0; j < 8; ++j) { v[i][j] = (float)h[j]; mx = fmaxf(mx, v[i][j]); }
        } else {
#pragma unroll
            for (int j = 0; j < 8; ++j) v[i][j] = -1e30f;
        }
    }
#pragma unroll
    for (int off = 1; off < 64; off <<= 1) mx = fmaxf(mx, __shfl_xor(mx, off));
    float sm = 0.f;
#pragma unroll
    for (int i = 0; i < 4; ++i)
#pragma unroll
        for (int j = 0; j < 8; ++j) { v[i][j] = __expf(v[i][j] - mx); sm += v[i][j]; }
#pragma unroll
    for (int off = 1; off < 64; off <<= 1) sm += __shfl_xor(sm, off);
    const float inv = 1.f / sm;
#pragma unroll
    for (int i = 0; i < 4; ++i) {
        int c0 = 8 * l + 512 * i;
        if (c0 < L) {
            union { f16x8 v8; f16x2 h[4]; } o;
#pragma unroll
            for (int j = 0; j < 4; ++j)
                o.h[j] = __builtin_amdgcn_cvt_pkrtz(v[i][2 * j] * inv, v[i][2 * j + 1] * inv);
            *reinterpret_cast<f16x8*>(row + c0) = o.v8;
        }
    }
}

// ===========================================================================
// Fallback path (R5): f32-staged GEMMs, used only if ws < 98MB.
// ===========================================================================
__global__ __launch_bounds__(256) void qr_gemm_kernel(
    const float* __restrict__ A, const float* __restrict__ B, float* C)
{
    __shared__ __align__(16) char sA[128 * 64];
    __shared__ __align__(16) char sB[128 * 64];
    const int t = threadIdx.x;
    const int w = t >> 6, l = t & 63;
    const int l15 = l & 15, lg = l >> 4;
    const int bm = blockIdx.x * 128;
    const int bn = blockIdx.y * 128;

    f32x4 acc[4][4];
#pragma unroll
    for (int i = 0; i < 4; ++i)
#pragma unroll
        for (int j = 0; j < 4; ++j) acc[i][j] = (f32x4){0.f, 0.f, 0.f, 0.f};

    const int kq = 4 * (t & 7);
    const int i2 = t >> 3;

    for (int kk = 0; kk < 1024; kk += 32) {
#pragma unroll
        for (int it = 0; it < 4; ++it) {
            int m = i2 + 32 * it;
            f32x4 x = *reinterpret_cast<const f32x4*>(&A[(size_t)(bm + m) * 1024 + kk + kq]);
            *reinterpret_cast<f16x4*>(sA + m * 64 + ((2 * kq) ^ (((m >> 1) & 3) << 4))) = cvt4h(x);
        }
        {
            int n0 = 4 * i2;
            f32x4 x[4];
#pragma unroll
            for (int r = 0; r < 4; ++r)
                x[r] = *reinterpret_cast<const f32x4*>(&B[(size_t)(kk + kq + r) * 1024 + bn + n0]);
#pragma unroll
            for (int j = 0; j < 4; ++j) {
                int n = n0 + j;
                union { f16x4 v; f16x2 h[2]; } s;
                s.h[0] = __builtin_amdgcn_cvt_pkrtz(x[0][j], x[1][j]);
                s.h[1] = __builtin_amdgcn_cvt_pkrtz(x[2][j], x[3][j]);
                *reinterpret_cast<f16x4*>(sB + n * 64 + ((2 * kq) ^ (((n >> 1) & 3) << 4))) = s.v;
            }
        }
        __syncthreads();
        f16x8 af[4], bfv[4];
        const int r0 = (w >> 1) * 64, c0 = (w & 1) * 64;
#pragma unroll
        for (int mt = 0; mt < 4; ++mt) {
            int m = r0 + 16 * mt + l15;
            af[mt] = *reinterpret_cast<f16x8*>(sA + m * 64 + ((16 * lg) ^ (((m >> 1) & 3) << 4)));
        }
#pragma unroll
        for (int nt = 0; nt < 4; ++nt) {
            int n = c0 + 16 * nt + l15;
            bfv[nt] = *reinterpret_cast<f16x8*>(sB + n * 64 + ((16 * lg) ^ (((n >> 1) & 3) << 4)));
        }
#pragma unroll
        for (int mt = 0; mt < 4; ++mt)
#pragma unroll
            for (int nt = 0; nt < 4; ++nt)
                acc[mt][nt] = MFMA16H(af[mt], bfv[nt], acc[mt][nt]);
        __syncthreads();
    }
#pragma unroll
    for (int mt = 0; mt < 4; ++mt)
#pragma unroll
        for (int nt = 0; nt < 4; ++nt)
#pragma unroll
            for (int rg = 0; rg < 4; ++rg) {
                int row = bm + (w >> 1) * 64 + 16 * mt + 4 * lg + rg;
                int col = bn + (w & 1) * 64 + 16 * nt + l15;
                C[(size_t)row * 1024 + col] = acc[mt][nt][rg];
            }
}

__global__ __launch_bounds__(256) void s_gemm_kernel(
    const float* __restrict__ Q, const float* __restrict__ enc, __fp16* __restrict__ S)
{
    __shared__ __align__(16) char sA[128 * 64];
    __shared__ __align__(16) char sB[128 * 64];
    const int t = threadIdx.x;
    const int w = t >> 6, l = t & 63;
    const int l15 = l & 15, lg = l >> 4;

    int rem = 135 - (int)blockIdx.x;
    int qt = 0;
    while (rem > qt) { rem -= qt + 1; ++qt; }
    const int kt = rem;
    const int b = blockIdx.y;
    const float* Arow = Q + ((size_t)b * 2048 + qt * 128) * 1024;
    const float* Brow = enc + ((size_t)b * 2048 + kt * 128) * 1024;

    f32x4 acc[4][4];
#pragma unroll
    for (int i = 0; i < 4; ++i)
#pragma unroll
        for (int j = 0; j < 4; ++j) acc[i][j] = (f32x4){0.f, 0.f, 0.f, 0.f};

    const int kq = 4 * (t & 7);
    const int i2 = t >> 3;

    for (int kk = 0; kk < 1024; kk += 32) {
#pragma unroll
        for (int it = 0; it < 4; ++it) {
            int m = i2 + 32 * it;
            int sw = (2 * kq) ^ (((m >> 1) & 3) << 4);
            f32x4 xa = *reinterpret_cast<const f32x4*>(&Arow[(size_t)m * 1024 + kk + kq]);
            f32x4 xb = *reinterpret_cast<const f32x4*>(&Brow[(size_t)m * 1024 + kk + kq]);
            *reinterpret_cast<f16x4*>(sA + m * 64 + sw) = cvt4h(xa);
            *reinterpret_cast<f16x4*>(sB + m * 64 + sw) = cvt4h(xb);
        }
        __syncthreads();
        f16x8 af[4], bfv[4];
        const int r0 = (w >> 1) * 64, c0 = (w & 1) * 64;
#pragma unroll
        for (int mt = 0; mt < 4; ++mt) {
            int m = r0 + 16 * mt + l15;
            af[mt] = *reinterpret_cast<f16x8*>(sA + m * 64 + ((16 * lg) ^ (((m >> 1) & 3) << 4)));
        }
#pragma unroll
        for (int nt = 0; nt < 4; ++nt) {
            int n = c0 + 16 * nt + l15;
            bfv[nt] = *reinterpret_cast<f16x8*>(sB + n * 64 + ((16 * lg) ^ (((n >> 1) & 3) << 4)));
        }
#pragma unroll
        for (int mt = 0; mt < 4; ++mt)
#pragma unroll
            for (int nt = 0; nt < 4; ++nt)
                acc[mt][nt] = MFMA16H(af[mt], bfv[nt], acc[mt][nt]);
        __syncthreads();
    }
    const int r0 = (w >> 1) * 64, c0 = (w & 1) * 64;
#pragma unroll
    for (int mt = 0; mt < 4; ++mt)
#pragma unroll
        for (int nt = 0; nt < 4; ++nt)
#pragma unroll
            for (int rg = 0; rg < 4; ++rg) {
                int rt = r0 + 16 * mt + 4 * lg + rg;
                int ct = c0 + 16 * nt + l15;
                float v = acc[mt][nt][rg];
                if (kt == qt && ct > rt) v = -30000.f;
                S[((size_t)b * 2048 + qt * 128 + rt) * 2048 + kt * 128 + ct] = (__fp16)v;
            }
}

__global__ __launch_bounds__(512) void pv_gemm_kernel(
    const __fp16* __restrict__ P, const float* __restrict__ enc, float* __restrict__ out)
{
    __shared__ __align__(16) char sA[128 * 128];
    __shared__ __align__(16) char sB[128 * 128];
    const int t = threadIdx.x;
    const int w = t >> 6, l = t & 63;
    const int l15 = l & 15, lg = (l >> 4) & 3;
    const int wq = w >> 2, wdv = w & 3;
    const int qtb = 15 - (int)blockIdx.x;
    const int dblk = blockIdx.y;
    const int b = blockIdx.z;
    const int q0 = 128 * qtb;
    const int nkv = 128 * (qtb + 1);
    const __fp16* Pbase = P + ((size_t)b * 2048 + q0) * 2048;
    const float* Eb = enc + (size_t)b * 2048 * 1024;

    f32x4 acc[4][2];
#pragma unroll
    for (int i = 0; i < 4; ++i)
#pragma unroll
        for (int j = 0; j < 2; ++j) acc[i][j] = (f32x4){0.f, 0.f, 0.f, 0.f};

    const int ar = t >> 2, aseg = t & 3;
    const int ba = t >> 5, bdq = t & 31;

    for (int kv0 = 0; kv0 < nkv; kv0 += 64) {
        __syncthreads();
        {
            const __fp16* src = Pbase + (size_t)ar * 2048 + kv0 + 16 * aseg;
            u32x4 v0 = *reinterpret_cast<const u32x4*>(src);
            u32x4 v1 = *reinterpret_cast<const u32x4*>(src + 8);
            const int sw = (ar & 7) << 4;
            *reinterpret_cast<u32x4*>(sA + ar * 128 + ((32 * aseg) ^ sw)) = v0;
            *reinterpret_cast<u32x4*>(sA + ar * 128 + ((32 * aseg + 16) ^ sw)) = v1;
        }
        {
            const float* src = Eb + (size_t)(kv0 + 4 * ba) * 1024 + 128 * dblk + 4 * bdq;
            f32x4 x0 = *reinterpret_cast<const f32x4*>(src);
            f32x4 x1 = *reinterpret_cast<const f32x4*>(src + 1024);
            f32x4 x2 = *reinterpret_cast<const f32x4*>(src + 2048);
            f32x4 x3 = *reinterpret_cast<const f32x4*>(src + 3072);
#pragma unroll
            for (int j = 0; j < 4; ++j) {
                int d = 4 * bdq + j;
                union { f16x4 v; f16x2 h[2]; } s;
                s.h[0] = __builtin_amdgcn_cvt_pkrtz(x0[j], x1[j]);
                s.h[1] = __builtin_amdgcn_cvt_pkrtz(x2[j], x3[j]);
                *reinterpret_cast<f16x4*>(sB + d * 128 + ((8 * ba) ^ ((d & 7) << 4))) = s.v;
            }
        }
        __syncthreads();
#pragma unroll
        for (int ks = 0; ks < 2; ++ks) {
            f16x8 afr[4], bfr[2];
#pragma unroll
            for (int mt = 0; mt < 4; ++mt) {
                int rr = 64 * wq + 16 * mt + l15;
                afr[mt] = *reinterpret_cast<f16x8*>(sA + rr * 128 + ((64 * ks + 16 * lg) ^ ((rr & 7) << 4)));
            }
#pragma unroll
            for (int nt = 0; nt < 2; ++nt) {
                int d = 32 * wdv + 16 * nt + l15;
                bfr[nt] = *reinterpret_cast<f16x8*>(sB + d * 128 + ((64 * ks + 16 * lg) ^ ((d & 7) << 4)));
            }
#pragma unroll
            for (int mt = 0; mt < 4; ++mt)
#pragma unroll
                for (int nt = 0; nt < 2; ++nt)
                    acc[mt][nt] = MFMA16H(afr[mt], bfr[nt], acc[mt][nt]);
        }
    }
#pragma unroll
    for (int mt = 0; mt < 4; ++mt)
#pragma unroll
        for (int nt = 0; nt < 2; ++nt)
#pragma unroll
            for (int rg = 0; rg < 4; ++rg) {
                size_t row = (size_t)b * 2048 + q0 + 64 * wq + 16 * mt + 4 * lg + rg;
                int col = 128 * dblk + 32 * wdv + 16 * nt + l15;
                out[row * 1024 + col] = acc[mt][nt][rg];
            }
}

// ---------------------------------------------------------------------------
extern "C" void kernel_launch(void* const* d_in, const int* in_sizes, int n_in,
                              void* d_out, int out_size, void* d_ws, size_t ws_size,
                              hipStream_t stream)
{
    const float* enc = (const float*)d_in[0];
    const float* R = (const float*)d_in[1];
    float* out = (float*)d_out;
    const size_t MB = 1u << 20;

    if (ws_size >= 98 * MB) {
        __fp16* S = (__fp16*)d_ws;                                  // 64MB
        __fp16* encT = (__fp16*)((char*)d_ws + 64 * MB);            // 32MB
        __fp16* Rt = (__fp16*)((char*)d_ws + 96 * MB);              // 2MB
        __fp16* Qh = (__fp16*)d_out;                                // 32MB
        __fp16* encH = (__fp16*)d_out + (size_t)16384 * 1024;       // 32MB

        transpose_cvt_kernel<<<dim3(32, 16, 8), 256, 0, stream>>>(enc, encT, encH, 2048, 1024);
        transpose_cvt_kernel<<<dim3(16, 16, 1), 256, 0, stream>>>(R, Rt, (__fp16*)nullptr, 1024, 1024);
        gemm_qr256<<<dim3(256), 512, 0, stream>>>(encH, Rt, Qh);
        gemm_s<<<dim3(1088), 256, 0, stream>>>(Qh, encH, S);
        softmax_kernel<<<dim3(512, 8), 256, 0, stream>>>(S);
        gemm_pv<<<dim3(1024), 256, 0, stream>>>(S, encT, out);
    } else {
        __fp16* S = (__fp16*)d_ws;
        qr_gemm_kernel<<<dim3(128, 8), 256, 0, stream>>>(enc, R, out);
        s_gemm_kernel<<<dim3(136, 8), 256, 0, stream>>>(out, enc, S);
        softmax_kernel<<<dim3(512, 8), 256, 0, stream>>>(S);
        pv_gemm_kernel<<<dim3(16, 8, 8), 512, 0, stream>>>(S, enc, out);
    }
}

// Round 11
// 177.820 us; speedup vs baseline: 1.1214x; 1.0308x over previous
//
#include <hip/hip_runtime.h>
#include <hip/hip_bf16.h>

// RelationAttn: out = softmax_causal((enc @ R) @ enc^T) @ enc
// enc: [8,2048,1024] f32, R: [1024,1024] f32, out: [8,2048,1024] f32
//
// R11: all three GEMMs on the 8-phase 256-row template (T3+T4+T5, counted
// vmcnt, 1 block/CU):
//   K1 qr256:  256x256 tiles, 256 blocks (verified R10)
//   K2 s256:   256x128 tiles over causal lower-tri, 576 blocks (uniform K)
//   K4 pv256:  256x128 tiles, paired (qtb,7-qtb) -> 256 blocks, uniform work
// S extent is 256-granular; softmax L likewise (masked cols -30000 -> 0).
// Fallback (ws < 98MB): R5 pipeline (f32-staged GEMMs, 128-granular softmax).

typedef __attribute__((ext_vector_type(4))) float f32x4;
typedef __attribute__((ext_vector_type(4))) unsigned u32x4;
typedef __attribute__((ext_vector_type(8))) __fp16 f16x8;
typedef __attribute__((ext_vector_type(4))) __fp16 f16x4;
typedef __attribute__((ext_vector_type(2))) __fp16 f16x2;

#define MFMA16H(A, B, C) __builtin_amdgcn_mfma_f32_16x16x32_f16(A, B, C, 0, 0, 0)

__device__ __forceinline__ f16x4 cvt4h(f32x4 a) {
    union { f16x4 v; f16x2 h[2]; } r;
    r.h[0] = __builtin_amdgcn_cvt_pkrtz(a[0], a[1]);
    r.h[1] = __builtin_amdgcn_cvt_pkrtz(a[2], a[3]);
    return r.v;
}

__device__ __forceinline__ void gload16(const void* g, void* l) {
    __builtin_amdgcn_global_load_lds(
        (const __attribute__((address_space(1))) unsigned*)g,
        (__attribute__((address_space(3))) unsigned*)l, 16, 0, 0);
}

#define BAR() do { __builtin_amdgcn_sched_barrier(0); \
                   __builtin_amdgcn_s_barrier();      \
                   __builtin_amdgcn_sched_barrier(0); } while (0)

// ---------------------------------------------------------------------------
// P0/P1: transpose + convert (unchanged)
// ---------------------------------------------------------------------------
__global__ __launch_bounds__(256) void transpose_cvt_kernel(
    const float* __restrict__ src, __fp16* __restrict__ dstT,
    __fp16* __restrict__ dstH, int R, int C)
{
    __shared__ __align__(16) char lt[64 * 128];
    const int t = threadIdx.x;
    const int bz = blockIdx.z;
    const int r0 = blockIdx.x * 64, c0 = blockIdx.y * 64;
    const size_t so = (size_t)bz * R * C;
    const int tr = t >> 4;
    const int tc4 = (t & 15) * 4;
#pragma unroll
    for (int p = 0; p < 4; ++p) {
        int rl = tr + 16 * p;
        f32x4 x = *(const f32x4*)(src + so + (size_t)(r0 + rl) * C + c0 + tc4);
        f16x4 h = cvt4h(x);
        if (dstH) *(f16x4*)(dstH + so + (size_t)(r0 + rl) * C + c0 + tc4) = h;
        *(f16x4*)(lt + rl * 128 + ((tc4 * 2) ^ ((rl & 7) << 4))) = h;
    }
    __syncthreads();
#pragma unroll
    for (int p = 0; p < 4; ++p) {
        int dl = tr + 16 * p;
#pragma unroll
        for (int j = 0; j < 4; ++j) {
            int kl = (t & 15) + 16 * j;
            __fp16 v = *(const __fp16*)(lt + kl * 128 + ((dl * 2) ^ ((kl & 7) << 4)));
            dstT[so + (size_t)(c0 + dl) * R + r0 + kl] = v;
        }
    }
}

// ---------------------------------------------------------------------------
// K1: 8-phase 256^2 GEMM (verified R10). 256 blocks, 512 thr.
// ---------------------------------------------------------------------------
__global__ __launch_bounds__(512, 2) void gemm_qr256(
    const __fp16* __restrict__ encH, const __fp16* __restrict__ Rt,
    __fp16* __restrict__ Qh)
{
    __shared__ __align__(16) char lds[131072];
    const int t = threadIdx.x;
    const int w = t >> 6, l = t & 63;
    const int l15 = l & 15, lg = (l >> 4) & 3;
    const int wr = w >> 2, wc = w & 3;
    const int bm = ((int)blockIdx.x >> 2) * 256;
    const int bn = ((int)blockIdx.x & 3) * 256;
    const __fp16* Ag = encH + (size_t)bm * 1024;
    const __fp16* Bg = Rt + (size_t)bn * 1024;

    const int srow = 32 * w + (l >> 2);
    const int slg = ((l & 3) - ((l >> 3) & 3)) & 3;
    const int slotr = ((l >> 4) + ((l & 15) >> 1)) & 3;

    f32x4 acc[8][4];
#pragma unroll
    for (int i = 0; i < 8; ++i)
#pragma unroll
        for (int j = 0; j < 4; ++j) acc[i][j] = (f32x4){0.f, 0.f, 0.f, 0.f};

    auto stage = [&](int op, int tile, int kh) {
        const __fp16* src = (op ? Bg : Ag) + (size_t)srow * 1024 + tile * 64 + kh * 32 + slg * 8;
        char* dst = lds + (tile & 1) * 65536 + op * 32768 + kh * 16384 + w * 2048;
        gload16(src, dst);
        gload16(src + (size_t)16 * 1024, dst + 1024);
    };
    auto rdA = [&](int buf, int ks, int mf) {
        return *(const f16x8*)(lds + buf * 65536 + ks * 16384
                               + (128 * wr + 16 * mf + l15) * 64 + slotr * 16);
    };
    auto rdB = [&](int buf, int ks, int nf) {
        return *(const f16x8*)(lds + buf * 65536 + 32768 + ks * 16384
                               + (64 * wc + 16 * nf + l15) * 64 + slotr * 16);
    };

    stage(0, 0, 0); stage(1, 0, 0); stage(0, 0, 1); stage(1, 0, 1);
    stage(0, 1, 0); stage(1, 1, 0);

    f16x8 afr[4], bfr[4];

#define MF16(mbase)                                                     \
    __builtin_amdgcn_s_setprio(1);                                      \
    _Pragma("unroll") for (int mf = 0; mf < 4; ++mf)                    \
        _Pragma("unroll") for (int nf = 0; nf < 4; ++nf)                \
            acc[(mbase) + mf][nf] = MFMA16H(afr[mf], bfr[nf], acc[(mbase) + mf][nf]); \
    __builtin_amdgcn_s_setprio(0);

    for (int i = 0; i < 8; ++i) {
        const bool lastI = (i == 7);
        asm volatile("s_waitcnt vmcnt(8)" ::: "memory");
        BAR();
#pragma unroll
        for (int nf = 0; nf < 4; ++nf) bfr[nf] = rdB(0, 0, nf);
#pragma unroll
        for (int mf = 0; mf < 4; ++mf) afr[mf] = rdA(0, 0, mf);
        stage(0, 2 * i + 1, 1);
        MF16(0)
        BAR();
#pragma unroll
        for (int mf = 0; mf < 4; ++mf) afr[mf] = rdA(0, 0, mf + 4);
        stage(1, 2 * i + 1, 1);
        MF16(4)
        asm volatile("s_waitcnt vmcnt(8)" ::: "memory");
        BAR();
#pragma unroll
        for (int nf = 0; nf < 4; ++nf) bfr[nf] = rdB(0, 1, nf);
#pragma unroll
        for (int mf = 0; mf < 4; ++mf) afr[mf] = rdA(0, 1, mf);
        if (!lastI) stage(0, 2 * i + 2, 0);
        MF16(0)
        BAR();
#pragma unroll
        for (int mf = 0; mf < 4; ++mf) afr[mf] = rdA(0, 1, mf + 4);
        if (!lastI) stage(1, 2 * i + 2, 0);
        MF16(4)
        if (!lastI) asm volatile("s_waitcnt vmcnt(8)" ::: "memory");
        else        asm volatile("s_waitcnt vmcnt(4)" ::: "memory");
        BAR();
#pragma unroll
        for (int nf = 0; nf < 4; ++nf) bfr[nf] = rdB(1, 0, nf);
#pragma unroll
        for (int mf = 0; mf < 4; ++mf) afr[mf] = rdA(1, 0, mf);
        if (!lastI) stage(0, 2 * i + 2, 1);
        MF16(0)
        BAR();
#pragma unroll
        for (int mf = 0; mf < 4; ++mf) afr[mf] = rdA(1, 0, mf + 4);
        if (!lastI) stage(1, 2 * i + 2, 1);
        MF16(4)
        if (!lastI) asm volatile("s_waitcnt vmcnt(8)" ::: "memory");
        else        asm volatile("s_waitcnt vmcnt(0)" ::: "memory");
        BAR();
#pragma unroll
        for (int nf = 0; nf < 4; ++nf) bfr[nf] = rdB(1, 1, nf);
#pragma unroll
        for (int mf = 0; mf < 4; ++mf) afr[mf] = rdA(1, 1, mf);
        if (!lastI) stage(0, 2 * i + 3, 0);
        MF16(0)
        BAR();
#pragma unroll
        for (int mf = 0; mf < 4; ++mf) afr[mf] = rdA(1, 1, mf + 4);
        if (!lastI) stage(1, 2 * i + 3, 0);
        MF16(4)
    }
#undef MF16

#pragma unroll
    for (int mf = 0; mf < 8; ++mf)
#pragma unroll
        for (int nf = 0; nf < 4; ++nf)
#pragma unroll
            for (int rg = 0; rg < 4; ++rg) {
                int rr = bm + 128 * wr + 16 * mf + 4 * lg + rg;
                int cc = bn + 64 * wc + 16 * nf + l15;
                Qh[(size_t)rr * 1024 + cc] = (__fp16)acc[mf][nf][rg];
            }
}

// ---------------------------------------------------------------------------
// 256x128-tile 8-phase core (4 phases/iter, vmcnt(6) counted).
// A: 256 rows (2 gloads/wave/stage), B: 128 rows (1 gload/wave/stage).
// Waves 4Mx2N, per-wave 64x64 (acc[4][4]). LDS 96KB, 1 block/CU.
// Region protocol: P1 reads buf0k0, stages buf1k1(2i+1); P2 reads buf0k1,
// stages buf0k0(2i+2); P3 reads buf1k0, stages buf0k1(2i+2); P4 reads buf1k1,
// stages buf1k0(2i+3). Uniform vmcnt(6); tail 6/6/3/0.
// CMODE: 1 = f16 out + causal mask; 2 = f32 out.
// ---------------------------------------------------------------------------
template <int CMODE>
__device__ __forceinline__ void core256x128(
    const __fp16* __restrict__ A, int ldA, const __fp16* __restrict__ B, int ldB,
    char* __restrict__ Cptr, int ldC, int K, int rowOff, int colOff, bool maskDiag)
{
    __shared__ __align__(16) char lds[98304];  // 2 bufs x (A 32KB + B 16KB)
    const int t = threadIdx.x;
    const int w = t >> 6, l = t & 63;
    const int l15 = l & 15, lg = (l >> 4) & 3;
    const int wr = w >> 1, wc = w & 1;

    const int srowA = 32 * w + (l >> 2);
    const int srowB = 16 * w + (l >> 2);
    const int slg = ((l & 3) - ((l >> 3) & 3)) & 3;
    const int slotr = ((l >> 4) + ((l & 15) >> 1)) & 3;

    f32x4 acc[4][4];
#pragma unroll
    for (int i = 0; i < 4; ++i)
#pragma unroll
        for (int j = 0; j < 4; ++j) acc[i][j] = (f32x4){0.f, 0.f, 0.f, 0.f};

    auto stageA = [&](int tile, int kh) {
        const __fp16* src = A + (size_t)srowA * ldA + tile * 64 + kh * 32 + slg * 8;
        char* dst = lds + (tile & 1) * 49152 + kh * 16384 + w * 2048;
        gload16(src, dst);
        gload16(src + (size_t)16 * ldA, dst + 1024);
    };
    auto stageB = [&](int tile, int kh) {
        const __fp16* src = B + (size_t)srowB * ldB + tile * 64 + kh * 32 + slg * 8;
        char* dst = lds + (tile & 1) * 49152 + 32768 + kh * 8192 + w * 1024;
        gload16(src, dst);
    };
    auto rdA = [&](int buf, int kh, int mf) {
        return *(const f16x8*)(lds + buf * 49152 + kh * 16384
                               + (64 * wr + 16 * mf + l15) * 64 + slotr * 16);
    };
    auto rdB = [&](int buf, int kh, int nf) {
        return *(const f16x8*)(lds + buf * 49152 + 32768 + kh * 8192
                               + (64 * wc + 16 * nf + l15) * 64 + slotr * 16);
    };

    // prologue: buf0k0, buf0k1, buf1k0 (3+3+3 = 9 loads/wave)
    stageA(0, 0); stageB(0, 0);
    stageA(0, 1); stageB(0, 1);
    stageA(1, 0); stageB(1, 0);

    f16x8 afr[4], bfr[4];
    const int nIter = K >> 7;  // 2 tiles of 64 per iter

#define MFPH()                                                          \
    __builtin_amdgcn_s_setprio(1);                                      \
    _Pragma("unroll") for (int mf = 0; mf < 4; ++mf)                    \
        _Pragma("unroll") for (int nf = 0; nf < 4; ++nf)                \
            acc[mf][nf] = MFMA16H(afr[mf], bfr[nf], acc[mf][nf]);       \
    __builtin_amdgcn_s_setprio(0);

    for (int i = 0; i < nIter; ++i) {
        const bool lastI = (i == nIter - 1);
        // P1: read buf0 kh0; stage buf1k1 (tile 2i+1)
        asm volatile("s_waitcnt vmcnt(6)" ::: "memory");
        BAR();
#pragma unroll
        for (int nf = 0; nf < 4; ++nf) bfr[nf] = rdB(0, 0, nf);
#pragma unroll
        for (int mf = 0; mf < 4; ++mf) afr[mf] = rdA(0, 0, mf);
        stageA(2 * i + 1, 1); stageB(2 * i + 1, 1);
        MFPH()
        // P2: read buf0 kh1; stage buf0k0 (tile 2i+2)
        asm volatile("s_waitcnt vmcnt(6)" ::: "memory");
        BAR();
#pragma unroll
        for (int nf = 0; nf < 4; ++nf) bfr[nf] = rdB(0, 1, nf);
#pragma unroll
        for (int mf = 0; mf < 4; ++mf) afr[mf] = rdA(0, 1, mf);
        if (!lastI) { stageA(2 * i + 2, 0); stageB(2 * i + 2, 0); }
        MFPH()
        // P3: read buf1 kh0; stage buf0k1 (tile 2i+2)
        if (!lastI) asm volatile("s_waitcnt vmcnt(6)" ::: "memory");
        else        asm volatile("s_waitcnt vmcnt(3)" ::: "memory");
        BAR();
#pragma unroll
        for (int nf = 0; nf < 4; ++nf) bfr[nf] = rdB(1, 0, nf);
#pragma unroll
        for (int mf = 0; mf < 4; ++mf) afr[mf] = rdA(1, 0, mf);
        if (!lastI) { stageA(2 * i + 2, 1); stageB(2 * i + 2, 1); }
        MFPH()
        // P4: read buf1 kh1; stage buf1k0 (tile 2i+3)
        if (!lastI) asm volatile("s_waitcnt vmcnt(6)" ::: "memory");
        else        asm volatile("s_waitcnt vmcnt(0)" ::: "memory");
        BAR();
#pragma unroll
        for (int nf = 0; nf < 4; ++nf) bfr[nf] = rdB(1, 1, nf);
#pragma unroll
        for (int mf = 0; mf < 4; ++mf) afr[mf] = rdA(1, 1, mf);
        if (!lastI) { stageA(2 * i + 3, 0); stageB(2 * i + 3, 0); }
        MFPH()
    }
#undef MFPH
    BAR();  // all LDS reads done before caller may re-enter (pv 2nd tile)

    // C/D layout: col = l15, row = 4*lg + rg
#pragma unroll
    for (int mf = 0; mf < 4; ++mf)
#pragma unroll
        for (int nf = 0; nf < 4; ++nf)
#pragma unroll
            for (int rg = 0; rg < 4; ++rg) {
                int rr = 64 * wr + 16 * mf + 4 * lg + rg;
                int cc = 64 * wc + 16 * nf + l15;
                float v = acc[mf][nf][rg];
                if (CMODE == 2) {
                    *(float*)(Cptr + ((size_t)rr * ldC + cc) * 4) = v;
                } else {
                    if (maskDiag && colOff + cc > rowOff + rr) v = -30000.f;
                    *(__fp16*)(Cptr + ((size_t)rr * ldC + cc) * 2) = (__fp16)v;
                }
            }
}

// K2: S = Q_h @ enc_h^T over causal lower-tri, 256x128 tiles. 576 blocks.
__global__ __launch_bounds__(512, 2) void gemm_s256(
    const __fp16* __restrict__ Qh, const __fp16* __restrict__ encH,
    __fp16* __restrict__ S)
{
    const int b = (int)blockIdx.x & 7;
    const int r = (int)blockIdx.x >> 3;   // 0..71
    int qt = 0;
    while (r >= (qt + 1) * (qt + 2)) ++qt;
    const int nt = r - qt * (qt + 1);     // 0..2qt+1
    const size_t bo = (size_t)b * 2048 * 1024;
    const size_t so = (size_t)b * 2048 * 2048;
    core256x128<1>(Qh + bo + (size_t)(256 * qt) * 1024, 1024,
                   encH + bo + (size_t)(128 * nt) * 1024, 1024,
                   (char*)(S + so + (size_t)(256 * qt) * 2048 + 128 * nt), 2048,
                   1024, 256 * qt, 128 * nt, (nt >> 1) == qt);
}

// K4: out = P @ enc_t^T, 256x128 tiles paired (qtb, 7-qtb). 256 blocks.
__global__ __launch_bounds__(512, 2) void gemm_pv256(
    const __fp16* __restrict__ P, const __fp16* __restrict__ encT,
    float* __restrict__ out)
{
    const int b = (int)blockIdx.x & 7;
    const int r = (int)blockIdx.x >> 3;   // 0..31
    const int a = r >> 3, dblk = r & 7;
    const size_t so = (size_t)b * 2048 * 2048;
    const size_t to = (size_t)b * 1024 * 2048;
    const size_t oo = (size_t)b * 2048 * 1024;
#pragma unroll
    for (int pass = 0; pass < 2; ++pass) {
        const int qtb = pass ? 7 - a : a;
        core256x128<2>(P + so + (size_t)(256 * qtb) * 2048, 2048,
                       encT + to + (size_t)(128 * dblk) * 2048, 2048,
                       (char*)(out + oo + (size_t)(256 * qtb) * 1024 + 128 * dblk), 1024,
                       256 * (qtb + 1), 0, 0, false);
    }
}

// ---------------------------------------------------------------------------
// K3: in-place row softmax over S (f16). L granularity = 1<<sh (8 main, 7 fb).
// ---------------------------------------------------------------------------
__global__ __launch_bounds__(256) void softmax_kernel(__fp16* __restrict__ S, int sh)
{
    const int t = threadIdx.x;
    const int wv = t >> 6, l = t & 63;
    const int r = blockIdx.x * 4 + wv;
    const int b = blockIdx.y;
    __fp16* row = S + ((size_t)b * 2048 + r) * 2048;
    const int L = ((r >> sh) + 1) << sh;

    float v[4][8];
    float mx = -1e30f;
#pragma unroll
    for (int i = 0; i < 4; ++i) {
        int c0 = 8 * l + 512 * i;
        if (c0 < L) {
            f16x8 h = *reinterpret_cast<const f16x8*>(row + c0);
#pragma unroll
            for (int j = 0; j < 8; ++j) { v[i][j] = (float)h[j]; mx = fmaxf(mx, v[i][j]); }
        } else {
#pragma unroll
            for (int j = 0; j < 8; ++j) v[i][j] = -1e30f;
        }
    }
#pragma unroll
    for (int off = 1; off < 64; off <<= 1) mx = fmaxf(mx, __shfl_xor(mx, off));
    float sm = 0.f;
#pragma unroll
    for (int i = 0; i < 4; ++i)
#pragma unroll
        for (int j = 0; j < 8; ++j) { v[i][j] = __expf(v[i][j] - mx); sm += v[i][j]; }
#pragma unroll
    for (int off = 1; off < 64; off <<= 1) sm += __shfl_xor(sm, off);
    const float inv = 1.f / sm;
#pragma unroll
    for (int i = 0; i < 4; ++i) {
        int c0 = 8 * l + 512 * i;
        if (c0 < L) {
            union { f16x8 v8; f16x2 h[4]; } o;
#pragma unroll
            for (int j = 0; j < 4; ++j)
                o.h[j] = __builtin_amdgcn_cvt_pkrtz(v[i][2 * j] * inv, v[i][2 * j + 1] * inv);
            *reinterpret_cast<f16x8*>(row + c0) = o.v8;
        }
    }
}

// ===========================================================================
// Fallback path (R5): f32-staged GEMMs, used only if ws < 98MB.
// ===========================================================================
__global__ __launch_bounds__(256) void qr_gemm_kernel(
    const float* __restrict__ A, const float* __restrict__ B, float* C)
{
    __shared__ __align__(16) char sA[128 * 64];
    __shared__ __align__(16) char sB[128 * 64];
    const int t = threadIdx.x;
    const int w = t >> 6, l = t & 63;
    const int l15 = l & 15, lg = l >> 4;
    const int bm = blockIdx.x * 128;
    const int bn = blockIdx.y * 128;

    f32x4 acc[4][4];
#pragma unroll
    for (int i = 0; i < 4; ++i)
#pragma unroll
        for (int j = 0; j < 4; ++j) acc[i][j] = (f32x4){0.f, 0.f, 0.f, 0.f};

    const int kq = 4 * (t & 7);
    const int i2 = t >> 3;

    for (int kk = 0; kk < 1024; kk += 32) {
#pragma unroll
        for (int it = 0; it < 4; ++it) {
            int m = i2 + 32 * it;
            f32x4 x = *reinterpret_cast<const f32x4*>(&A[(size_t)(bm + m) * 1024 + kk + kq]);
            *reinterpret_cast<f16x4*>(sA + m * 64 + ((2 * kq) ^ (((m >> 1) & 3) << 4))) = cvt4h(x);
        }
        {
            int n0 = 4 * i2;
            f32x4 x[4];
#pragma unroll
            for (int r = 0; r < 4; ++r)
                x[r] = *reinterpret_cast<const f32x4*>(&B[(size_t)(kk + kq + r) * 1024 + bn + n0]);
#pragma unroll
            for (int j = 0; j < 4; ++j) {
                int n = n0 + j;
                union { f16x4 v; f16x2 h[2]; } s;
                s.h[0] = __builtin_amdgcn_cvt_pkrtz(x[0][j], x[1][j]);
                s.h[1] = __builtin_amdgcn_cvt_pkrtz(x[2][j], x[3][j]);
                *reinterpret_cast<f16x4*>(sB + n * 64 + ((2 * kq) ^ (((n >> 1) & 3) << 4))) = s.v;
            }
        }
        __syncthreads();
        f16x8 af[4], bfv[4];
        const int r0 = (w >> 1) * 64, c0 = (w & 1) * 64;
#pragma unroll
        for (int mt = 0; mt < 4; ++mt) {
            int m = r0 + 16 * mt + l15;
            af[mt] = *reinterpret_cast<f16x8*>(sA + m * 64 + ((16 * lg) ^ (((m >> 1) & 3) << 4)));
        }
#pragma unroll
        for (int nt = 0; nt < 4; ++nt) {
            int n = c0 + 16 * nt + l15;
            bfv[nt] = *reinterpret_cast<f16x8*>(sB + n * 64 + ((16 * lg) ^ (((n >> 1) & 3) << 4)));
        }
#pragma unroll
        for (int mt = 0; mt < 4; ++mt)
#pragma unroll
            for (int nt = 0; nt < 4; ++nt)
                acc[mt][nt] = MFMA16H(af[mt], bfv[nt], acc[mt][nt]);
        __syncthreads();
    }
#pragma unroll
    for (int mt = 0; mt < 4; ++mt)
#pragma unroll
        for (int nt = 0; nt < 4; ++nt)
#pragma unroll
            for (int rg = 0; rg < 4; ++rg) {
                int row = bm + (w >> 1) * 64 + 16 * mt + 4 * lg + rg;
                int col = bn + (w & 1) * 64 + 16 * nt + l15;
                C[(size_t)row * 1024 + col] = acc[mt][nt][rg];
            }
}

__global__ __launch_bounds__(256) void s_gemm_kernel(
    const float* __restrict__ Q, const float* __restrict__ enc, __fp16* __restrict__ S)
{
    __shared__ __align__(16) char sA[128 * 64];
    __shared__ __align__(16) char sB[128 * 64];
    const int t = threadIdx.x;
    const int w = t >> 6, l = t & 63;
    const int l15 = l & 15, lg = l >> 4;

    int rem = 135 - (int)blockIdx.x;
    int qt = 0;
    while (rem > qt) { rem -= qt + 1; ++qt; }
    const int kt = rem;
    const int b = blockIdx.y;
    const float* Arow = Q + ((size_t)b * 2048 + qt * 128) * 1024;
    const float* Brow = enc + ((size_t)b * 2048 + kt * 128) * 1024;

    f32x4 acc[4][4];
#pragma unroll
    for (int i = 0; i < 4; ++i)
#pragma unroll
        for (int j = 0; j < 4; ++j) acc[i][j] = (f32x4){0.f, 0.f, 0.f, 0.f};

    const int kq = 4 * (t & 7);
    const int i2 = t >> 3;

    for (int kk = 0; kk < 1024; kk += 32) {
#pragma unroll
        for (int it = 0; it < 4; ++it) {
            int m = i2 + 32 * it;
            int sw = (2 * kq) ^ (((m >> 1) & 3) << 4);
            f32x4 xa = *reinterpret_cast<const f32x4*>(&Arow[(size_t)m * 1024 + kk + kq]);
            f32x4 xb = *reinterpret_cast<const f32x4*>(&Brow[(size_t)m * 1024 + kk + kq]);
            *reinterpret_cast<f16x4*>(sA + m * 64 + sw) = cvt4h(xa);
            *reinterpret_cast<f16x4*>(sB + m * 64 + sw) = cvt4h(xb);
        }
        __syncthreads();
        f16x8 af[4], bfv[4];
        const int r0 = (w >> 1) * 64, c0 = (w & 1) * 64;
#pragma unroll
        for (int mt = 0; mt < 4; ++mt) {
            int m = r0 + 16 * mt + l15;
            af[mt] = *reinterpret_cast<f16x8*>(sA + m * 64 + ((16 * lg) ^ (((m >> 1) & 3) << 4)));
        }
#pragma unroll
        for (int nt = 0; nt < 4; ++nt) {
            int n = c0 + 16 * nt + l15;
            bfv[nt] = *reinterpret_cast<f16x8*>(sB + n * 64 + ((16 * lg) ^ (((n >> 1) & 3) << 4)));
        }
#pragma unroll
        for (int mt = 0; mt < 4; ++mt)
#pragma unroll
            for (int nt = 0; nt < 4; ++nt)
                acc[mt][nt] = MFMA16H(af[mt], bfv[nt], acc[mt][nt]);
        __syncthreads();
    }
    const int r0 = (w >> 1) * 64, c0 = (w & 1) * 64;
#pragma unroll
    for (int mt = 0; mt < 4; ++mt)
#pragma unroll
        for (int nt = 0; nt < 4; ++nt)
#pragma unroll
            for (int rg = 0; rg < 4; ++rg) {
                int rt = r0 + 16 * mt + 4 * lg + rg;
                int ct = c0 + 16 * nt + l15;
                float v = acc[mt][nt][rg];
                if (kt == qt && ct > rt) v = -30000.f;
                S[((size_t)b * 2048 + qt * 128 + rt) * 2048 + kt * 128 + ct] = (__fp16)v;
            }
}

__global__ __launch_bounds__(512) void pv_gemm_kernel(
    const __fp16* __restrict__ P, const float* __restrict__ enc, float* __restrict__ out)
{
    __shared__ __align__(16) char sA[128 * 128];
    __shared__ __align__(16) char sB[128 * 128];
    const int t = threadIdx.x;
    const int w = t >> 6, l = t & 63;
    const int l15 = l & 15, lg = (l >> 4) & 3;
    const int wq = w >> 2, wdv = w & 3;
    const int qtb = 15 - (int)blockIdx.x;
    const int dblk = blockIdx.y;
    const int b = blockIdx.z;
    const int q0 = 128 * qtb;
    const int nkv = 128 * (qtb + 1);
    const __fp16* Pbase = P + ((size_t)b * 2048 + q0) * 2048;
    const float* Eb = enc + (size_t)b * 2048 * 1024;

    f32x4 acc[4][2];
#pragma unroll
    for (int i = 0; i < 4; ++i)
#pragma unroll
        for (int j = 0; j < 2; ++j) acc[i][j] = (f32x4){0.f, 0.f, 0.f, 0.f};

    const int ar = t >> 2, aseg = t & 3;
    const int ba = t >> 5, bdq = t & 31;

    for (int kv0 = 0; kv0 < nkv; kv0 += 64) {
        __syncthreads();
        {
            const __fp16* src = Pbase + (size_t)ar * 2048 + kv0 + 16 * aseg;
            u32x4 v0 = *reinterpret_cast<const u32x4*>(src);
            u32x4 v1 = *reinterpret_cast<const u32x4*>(src + 8);
            const int sw = (ar & 7) << 4;
            *reinterpret_cast<u32x4*>(sA + ar * 128 + ((32 * aseg) ^ sw)) = v0;
            *reinterpret_cast<u32x4*>(sA + ar * 128 + ((32 * aseg + 16) ^ sw)) = v1;
        }
        {
            const float* src = Eb + (size_t)(kv0 + 4 * ba) * 1024 + 128 * dblk + 4 * bdq;
            f32x4 x0 = *reinterpret_cast<const f32x4*>(src);
            f32x4 x1 = *reinterpret_cast<const f32x4*>(src + 1024);
            f32x4 x2 = *reinterpret_cast<const f32x4*>(src + 2048);
            f32x4 x3 = *reinterpret_cast<const f32x4*>(src + 3072);
#pragma unroll
            for (int j = 0; j < 4; ++j) {
                int d = 4 * bdq + j;
                union { f16x4 v; f16x2 h[2]; } s;
                s.h[0] = __builtin_amdgcn_cvt_pkrtz(x0[j], x1[j]);
                s.h[1] = __builtin_amdgcn_cvt_pkrtz(x2[j], x3[j]);
                *reinterpret_cast<f16x4*>(sB + d * 128 + ((8 * ba) ^ ((d & 7) << 4))) = s.v;
            }
        }
        __syncthreads();
#pragma unroll
        for (int ks = 0; ks < 2; ++ks) {
            f16x8 afr[4], bfr[2];
#pragma unroll
            for (int mt = 0; mt < 4; ++mt) {
                int rr = 64 * wq + 16 * mt + l15;
                afr[mt] = *reinterpret_cast<f16x8*>(sA + rr * 128 + ((64 * ks + 16 * lg) ^ ((rr & 7) << 4)));
            }
#pragma unroll
            for (int nt = 0; nt < 2; ++nt) {
                int d = 32 * wdv + 16 * nt + l15;
                bfr[nt] = *reinterpret_cast<f16x8*>(sB + d * 128 + ((64 * ks + 16 * lg) ^ ((d & 7) << 4)));
            }
#pragma unroll
            for (int mt = 0; mt < 4; ++mt)
#pragma unroll
                for (int nt = 0; nt < 2; ++nt)
                    acc[mt][nt] = MFMA16H(afr[mt], bfr[nt], acc[mt][nt]);
        }
    }
#pragma unroll
    for (int mt = 0; mt < 4; ++mt)
#pragma unroll
        for (int nt = 0; nt < 2; ++nt)
#pragma unroll
            for (int rg = 0; rg < 4; ++rg) {
                size_t row = (size_t)b * 2048 + q0 + 64 * wq + 16 * mt + 4 * lg + rg;
                int col = 128 * dblk + 32 * wdv + 16 * nt + l15;
                out[row * 1024 + col] = acc[mt][nt][rg];
            }
}

// ---------------------------------------------------------------------------
extern "C" void kernel_launch(void* const* d_in, const int* in_sizes, int n_in,
                              void* d_out, int out_size, void* d_ws, size_t ws_size,
                              hipStream_t stream)
{
    const float* enc = (const float*)d_in[0];
    const float* R = (const float*)d_in[1];
    float* out = (float*)d_out;
    const size_t MB = 1u << 20;

    if (ws_size >= 98 * MB) {
        __fp16* S = (__fp16*)d_ws;                                  // 64MB
        __fp16* encT = (__fp16*)((char*)d_ws + 64 * MB);            // 32MB
        __fp16* Rt = (__fp16*)((char*)d_ws + 96 * MB);              // 2MB
        __fp16* Qh = (__fp16*)d_out;                                // 32MB
        __fp16* encH = (__fp16*)d_out + (size_t)16384 * 1024;       // 32MB

        transpose_cvt_kernel<<<dim3(32, 16, 8), 256, 0, stream>>>(enc, encT, encH, 2048, 1024);
        transpose_cvt_kernel<<<dim3(16, 16, 1), 256, 0, stream>>>(R, Rt, (__fp16*)nullptr, 1024, 1024);
        gemm_qr256<<<dim3(256), 512, 0, stream>>>(encH, Rt, Qh);
        gemm_s256<<<dim3(576), 512, 0, stream>>>(Qh, encH, S);
        softmax_kernel<<<dim3(512, 8), 256, 0, stream>>>(S, 8);
        gemm_pv256<<<dim3(256), 512, 0, stream>>>(S, encT, out);
    } else {
        __fp16* S = (__fp16*)d_ws;
        qr_gemm_kernel<<<dim3(128, 8), 256, 0, stream>>>(enc, R, out);
        s_gemm_kernel<<<dim3(136, 8), 256, 0, stream>>>(out, enc, S);
        softmax_kernel<<<dim3(512, 8), 256, 0, stream>>>(S, 7);
        pv_gemm_kernel<<<dim3(16, 8, 8), 512, 0, stream>>>(S, enc, out);
    }
}